// Round 1
// baseline (2102.064 us; speedup 1.0000x reference)
//
#include <hip/hip_runtime.h>

#define BN 13248
#define NE 211968

__device__ __forceinline__ float fast_tanh(float x) {
  float e2 = __expf(2.f * x);
  return 1.f - 2.f / (e2 + 1.f);   // inf-safe: e2=inf -> 1, e2=0 -> -1
}
__device__ __forceinline__ float fast_sig(float x) {
  return 1.f / (1.f + __expf(-x));
}

// ---------------- CSR build ----------------
__global__ void k_count(const int* __restrict__ src, const int* __restrict__ dst,
                        int* __restrict__ cur_f, int* __restrict__ cur_b) {
  int e = blockIdx.x * 256 + threadIdx.x;
  if (e < NE) {
    atomicAdd(&cur_f[dst[e]], 1);
    atomicAdd(&cur_b[src[e]], 1);
  }
}

__global__ void k_scan(int* __restrict__ cur_f, int* __restrict__ row_f,
                       int* __restrict__ cur_b, int* __restrict__ row_b) {
  __shared__ int sdata[1024];
  int tid = threadIdx.x;
  for (int which = 0; which < 2; ++which) {
    int* cnt = which ? cur_b : cur_f;
    int* row = which ? row_b : row_f;
    int base = tid * 13;
    int vals[13];
    int tot = 0;
    for (int k = 0; k < 13; ++k) {
      int idx = base + k;
      int v = (idx < BN) ? cnt[idx] : 0;
      vals[k] = v; tot += v;
    }
    sdata[tid] = tot;
    __syncthreads();
    for (int off = 1; off < 1024; off <<= 1) {
      int add = (tid >= off) ? sdata[tid - off] : 0;
      __syncthreads();
      sdata[tid] += add;
      __syncthreads();
    }
    int running = sdata[tid] - tot;  // exclusive
    for (int k = 0; k < 13; ++k) {
      int idx = base + k;
      if (idx < BN) { row[idx] = running; cnt[idx] = running; running += vals[k]; }
    }
    if (tid == 1023) row[BN] = sdata[1023];
    __syncthreads();
  }
}

__global__ void k_fill(const int* __restrict__ src, const int* __restrict__ dst,
                       const float* __restrict__ w,
                       int* __restrict__ cur_f, int* __restrict__ col_f, float* __restrict__ w_f,
                       int* __restrict__ cur_b, int* __restrict__ col_b, float* __restrict__ w_b) {
  int e = blockIdx.x * 256 + threadIdx.x;
  if (e < NE) {
    int s = src[e], t = dst[e];
    float wv = w[e];
    int p = atomicAdd(&cur_f[t], 1); col_f[p] = s; w_f[p] = wv;
    int q = atomicAdd(&cur_b[s], 1); col_b[q] = t; w_b[q] = wv;
  }
}

// ---------------- init linear: h[tau][n][c] = x[n][tau][:] @ init_w + init_b ----------------
__global__ void k_init(const float* __restrict__ x, const float* __restrict__ iw,
                       const float* __restrict__ ib, float* __restrict__ h) {
  int idx = blockIdx.x * 256 + threadIdx.x;
  if (idx >= BN * 13 * 32) return;
  int c = idx & 31;
  int r = idx >> 5;          // r = tau*BN + n
  int n = r % BN;
  int tau = r / BN;
  float x0 = x[(n * 13 + tau) * 2 + 0];
  float x1 = x[(n * 13 + tau) * 2 + 1];
  h[idx] = fmaf(x0, iw[c], fmaf(x1, iw[32 + c], ib[c]));
}

// ---------------- gated TCN: t[tau][n][co] = tanh(conv_f) * sigmoid(conv_g) ----------------
template<int LIN, int D>
__global__ __launch_bounds__(256) void k_tcn(const float* __restrict__ h_in, float* __restrict__ t_out,
    const float* __restrict__ fw, const float* __restrict__ fb,
    const float* __restrict__ gw, const float* __restrict__ gb) {
  constexpr int LOUT = LIN - D;
  __shared__ __align__(16) float wq[32 * 32 * 4];   // [(ci*32+co)*4 + {f0,f1,g0,g1}]
  __shared__ float hl[8][LIN * 32];
  int tid = threadIdx.x;
  for (int f = tid; f < 4096; f += 256) {
    int e = f & 3, co = (f >> 2) & 31, ci = f >> 7;
    const float* srcw = (e < 2) ? fw : gw;
    wq[f] = srcw[(co * 32 + ci) * 2 + (e & 1)];
  }
  int n0 = blockIdx.x * 8;
  for (int i = tid; i < 8 * LIN * 32; i += 256) {
    int c = i & 31, r = i >> 5;
    int nl = r / LIN, tau = r % LIN;
    int n = n0 + nl;
    hl[nl][tau * 32 + c] = (n < BN) ? h_in[(tau * BN + n) * 32 + c] : 0.f;
  }
  __syncthreads();
  int nl = tid >> 5, co = tid & 31;
  int n = n0 + nl;
  float accf[LOUT], accg[LOUT];
  float fbv = fb[co], gbv = gb[co];
#pragma unroll
  for (int j = 0; j < LOUT; ++j) { accf[j] = fbv; accg[j] = gbv; }
#pragma unroll
  for (int ci = 0; ci < 32; ++ci) {
    float4 wv = *(const float4*)&wq[(ci * 32 + co) * 4];
    float xr[LIN];
#pragma unroll
    for (int t = 0; t < LIN; ++t) xr[t] = hl[nl][t * 32 + ci];
#pragma unroll
    for (int j = 0; j < LOUT; ++j) {
      accf[j] = fmaf(xr[j], wv.x, accf[j]);
      accf[j] = fmaf(xr[j + D], wv.y, accf[j]);
      accg[j] = fmaf(xr[j], wv.z, accg[j]);
      accg[j] = fmaf(xr[j + D], wv.w, accg[j]);
    }
  }
  if (n < BN) {
#pragma unroll
    for (int j = 0; j < LOUT; ++j) {
      float v = fast_tanh(accf[j]) * fast_sig(accg[j]);
      t_out[(j * BN + n) * 32 + co] = v;
    }
  }
}

// ------------- diffusion conv: aggregate (6 hop-weighted CSR gathers) + 192x32 matmul + residual -------------
template<int LOUT, int D>
__global__ __launch_bounds__(256) void k_agg(const float* __restrict__ t_in,
    const float* __restrict__ h_in, float* __restrict__ h_out, float* __restrict__ lastcol,
    const int* __restrict__ row_f, const int* __restrict__ col_f, const float* __restrict__ w_f,
    const int* __restrict__ row_b, const int* __restrict__ col_b, const float* __restrict__ w_b,
    const float* __restrict__ W, const float* __restrict__ bias) {
  constexpr int NCHUNK = (LOUT + 3) / 4;
  __shared__ __align__(16) float Wt[6 * 32 * 36];        // Wt[a][co][ci], pad 36
  __shared__ __align__(16) float zl[8][6][4][32];
  int tid = threadIdx.x;
  for (int f = tid; f < 6144; f += 256) {
    int a = f >> 10, ci = (f >> 5) & 31, co = f & 31;
    Wt[a * 1152 + co * 36 + ci] = W[f];
  }
  int nl = tid >> 5, c = tid & 31;
  int n = blockIdx.x * 8 + nl;
  bool valid = n < BN;
  int ef0 = 0, ef1 = 0, eb0 = 0, eb1 = 0;
  if (valid) { ef0 = row_f[n]; ef1 = row_f[n + 1]; eb0 = row_b[n]; eb1 = row_b[n + 1]; }
  float bco = bias[c];
  __syncthreads();
#pragma unroll
  for (int ch = 0; ch < NCHUNK; ++ch) {
    const int tau0 = ch * 4;
    float acc[6][4];
#pragma unroll
    for (int a = 0; a < 6; ++a)
#pragma unroll
      for (int j = 0; j < 4; ++j) acc[a][j] = 0.f;
    if (valid) {
      for (int e = ef0; e < ef1; ++e) {
        int s = col_f[e];
        float w1 = w_f[e], w2 = w1 * w1, w3 = w2 * w1;
#pragma unroll
        for (int j = 0; j < 4; ++j) {
          if (tau0 + j < LOUT) {
            float v = t_in[((tau0 + j) * BN + s) * 32 + c];
            acc[0][j] = fmaf(w1, v, acc[0][j]);
            acc[1][j] = fmaf(w2, v, acc[1][j]);
            acc[2][j] = fmaf(w3, v, acc[2][j]);
          }
        }
      }
      for (int e = eb0; e < eb1; ++e) {
        int s = col_b[e];
        float w1 = w_b[e], w2 = w1 * w1, w3 = w2 * w1;
#pragma unroll
        for (int j = 0; j < 4; ++j) {
          if (tau0 + j < LOUT) {
            float v = t_in[((tau0 + j) * BN + s) * 32 + c];
            acc[3][j] = fmaf(w1, v, acc[3][j]);
            acc[4][j] = fmaf(w2, v, acc[4][j]);
            acc[5][j] = fmaf(w3, v, acc[5][j]);
          }
        }
      }
    }
#pragma unroll
    for (int a = 0; a < 6; ++a)
#pragma unroll
      for (int j = 0; j < 4; ++j) zl[nl][a][j][c] = acc[a][j];
    __syncthreads();
    // matmul: g[tau][co] = sum_a sum_ci z[a][tau][ci] * W[a][ci][co], lane = co = c
    float g[4] = { bco, bco, bco, bco };
#pragma unroll
    for (int a = 0; a < 6; ++a) {
      const float4* wp = (const float4*)&Wt[a * 1152 + c * 36];
      float4 w0 = wp[0], w1v = wp[1], w2v = wp[2], w3v = wp[3];
      float4 w4 = wp[4], w5 = wp[5], w6 = wp[6], w7 = wp[7];
#pragma unroll
      for (int j = 0; j < 4; ++j) {
        if (tau0 + j < LOUT) {
          const float4* zp = (const float4*)&zl[nl][a][j][0];
          float4 z0 = zp[0], z1 = zp[1], z2 = zp[2], z3 = zp[3];
          float4 z4 = zp[4], z5 = zp[5], z6 = zp[6], z7 = zp[7];
          float gg = g[j];
          gg = fmaf(z0.x, w0.x, gg); gg = fmaf(z0.y, w0.y, gg); gg = fmaf(z0.z, w0.z, gg); gg = fmaf(z0.w, w0.w, gg);
          gg = fmaf(z1.x, w1v.x, gg); gg = fmaf(z1.y, w1v.y, gg); gg = fmaf(z1.z, w1v.z, gg); gg = fmaf(z1.w, w1v.w, gg);
          gg = fmaf(z2.x, w2v.x, gg); gg = fmaf(z2.y, w2v.y, gg); gg = fmaf(z2.z, w2v.z, gg); gg = fmaf(z2.w, w2v.w, gg);
          gg = fmaf(z3.x, w3v.x, gg); gg = fmaf(z3.y, w3v.y, gg); gg = fmaf(z3.z, w3v.z, gg); gg = fmaf(z3.w, w3v.w, gg);
          gg = fmaf(z4.x, w4.x, gg); gg = fmaf(z4.y, w4.y, gg); gg = fmaf(z4.z, w4.z, gg); gg = fmaf(z4.w, w4.w, gg);
          gg = fmaf(z5.x, w5.x, gg); gg = fmaf(z5.y, w5.y, gg); gg = fmaf(z5.z, w5.z, gg); gg = fmaf(z5.w, w5.w, gg);
          gg = fmaf(z6.x, w6.x, gg); gg = fmaf(z6.y, w6.y, gg); gg = fmaf(z6.z, w6.z, gg); gg = fmaf(z6.w, w6.w, gg);
          gg = fmaf(z7.x, w7.x, gg); gg = fmaf(z7.y, w7.y, gg); gg = fmaf(z7.z, w7.z, gg); gg = fmaf(z7.w, w7.w, gg);
          g[j] = gg;
        }
      }
    }
#pragma unroll
    for (int j = 0; j < 4; ++j) {
      int tau = tau0 + j;
      if (tau < LOUT && valid) {
        float r = h_in[((tau + D) * BN + n) * 32 + c];   // residual: last LOUT steps
        float o = g[j] + r;
        h_out[(tau * BN + n) * 32 + c] = o;
        if (tau == LOUT - 1) lastcol[n * 32 + c] = o;
      }
    }
    __syncthreads();
  }
}

// ------------- fused head: skip-sum -> relu -> 256x512 -> relu -> 512x12 -------------
__global__ __launch_bounds__(256) void k_final(const float* __restrict__ lastcol,
    const float* __restrict__ skip_w, const float* __restrict__ skip_b,
    const float* __restrict__ w0, const float* __restrict__ b0,
    const float* __restrict__ w1, const float* __restrict__ b1,
    float* __restrict__ out) {
  __shared__ float z[16 * 256];      // lastcols then relu(skip)
  __shared__ float ws[32 * 257];     // skip_w tile, then hidden (stride 514)
  int tid = threadIdx.x;
  int n0 = blockIdx.x * 16;
  // Phase A: load last columns for 16 nodes: z[k][l*32+c]
  {
    int l = tid >> 5, c = tid & 31;
    for (int k = 0; k < 16; ++k) {
      int n = n0 + k;
      z[k * 256 + tid] = (n < BN) ? lastcol[(l * BN + n) * 32 + c] : 0.f;
    }
  }
  __syncthreads();
  // Phase B: skip[k][j=tid] = sum_l sum_c z[k][l*32+c] * skip_w[l][j][c]
  float acc[16];
#pragma unroll
  for (int k = 0; k < 16; ++k) acc[k] = 0.f;
  for (int ll = 0; ll < 8; ++ll) {
    __syncthreads();
    for (int f = tid; f < 8192; f += 256) {
      int cc = f & 31, jj = f >> 5;
      ws[cc * 257 + jj] = skip_w[(ll * 256 + jj) * 32 + cc];
    }
    __syncthreads();
#pragma unroll
    for (int k = 0; k < 16; ++k) {
      float a = acc[k];
#pragma unroll
      for (int cc = 0; cc < 32; ++cc)
        a = fmaf(z[k * 256 + ll * 32 + cc], ws[cc * 257 + tid], a);
      acc[k] = a;
    }
  }
  float bsum = 0.f;
  for (int ll = 0; ll < 8; ++ll) bsum += skip_b[ll * 256 + tid];
  __syncthreads();
#pragma unroll
  for (int k = 0; k < 16; ++k) z[k * 256 + tid] = fmaxf(acc[k] + bsum, 0.f);
  __syncthreads();
  // Phase C: hidden[k][t] for t=tid, tid+256
  float h0a[16], h1a[16];
  float b0v0 = b0[tid], b0v1 = b0[tid + 256];
#pragma unroll
  for (int k = 0; k < 16; ++k) { h0a[k] = b0v0; h1a[k] = b0v1; }
  for (int j = 0; j < 256; ++j) {
    float wv0 = w0[j * 512 + tid];
    float wv1 = w0[j * 512 + tid + 256];
#pragma unroll
    for (int k = 0; k < 16; ++k) {
      float sv = z[k * 256 + j];
      h0a[k] = fmaf(sv, wv0, h0a[k]);
      h1a[k] = fmaf(sv, wv1, h1a[k]);
    }
  }
  __syncthreads();
#pragma unroll
  for (int k = 0; k < 16; ++k) {
    ws[k * 514 + tid] = fmaxf(h0a[k], 0.f);
    ws[k * 514 + tid + 256] = fmaxf(h1a[k], 0.f);
  }
  __syncthreads();
  // Phase D: out[k][j] = hidden[k][:] @ out1_w[:, j] + b1[j]
  if (tid < 192) {
    int k = tid / 12, j = tid % 12;
    int n = n0 + k;
    if (n < BN) {
      float a = b1[j];
      for (int t = 0; t < 512; ++t)
        a = fmaf(ws[k * 514 + t], w1[t * 12 + j], a);
      out[n * 12 + j] = a;
    }
  }
}

extern "C" void kernel_launch(void* const* d_in, const int* in_sizes, int n_in,
                              void* d_out, int out_size, void* d_ws, size_t ws_size,
                              hipStream_t stream) {
  const float* x      = (const float*)d_in[0];
  const int*   esrc   = (const int*)d_in[1];
  const int*   edst   = (const int*)d_in[2];
  const float* ew     = (const float*)d_in[3];
  const float* init_w = (const float*)d_in[4];
  const float* init_b = (const float*)d_in[5];
  const float* filt_w = (const float*)d_in[6];
  const float* filt_b = (const float*)d_in[7];
  const float* gate_w = (const float*)d_in[8];
  const float* gate_b = (const float*)d_in[9];
  const float* gcn_w  = (const float*)d_in[10];
  const float* gcn_b  = (const float*)d_in[11];
  const float* skip_w = (const float*)d_in[12];
  const float* skip_b = (const float*)d_in[13];
  const float* w0     = (const float*)d_in[14];
  const float* b0     = (const float*)d_in[15];
  const float* w1     = (const float*)d_in[16];
  const float* b1     = (const float*)d_in[17];
  float* out = (float*)d_out;

  float* base = (float*)d_ws;
  float* hA      = base;                       // 13*BN*32
  float* hB      = hA + 13 * BN * 32;          // 13*BN*32
  float* tbuf    = hB + 13 * BN * 32;          // 12*BN*32
  float* lastcol = tbuf + 12 * BN * 32;        // 8*BN*32
  int* row_f = (int*)(lastcol + 8 * BN * 32);  // BN+1
  int* row_b = row_f + (BN + 1);               // BN+1
  int* cur_f = row_b + (BN + 1);               // BN
  int* cur_b = cur_f + BN;                     // BN
  int* col_f = cur_b + BN;                     // NE
  int* col_b = col_f + NE;                     // NE
  float* wgt_f = (float*)(col_b + NE);         // NE
  float* wgt_b = wgt_f + NE;                   // NE

  hipMemsetAsync(cur_f, 0, 2 * BN * sizeof(int), stream);
  const int egrid = (NE + 255) / 256;
  k_count<<<egrid, 256, 0, stream>>>(esrc, edst, cur_f, cur_b);
  k_scan<<<1, 1024, 0, stream>>>(cur_f, row_f, cur_b, row_b);
  k_fill<<<egrid, 256, 0, stream>>>(esrc, edst, ew, cur_f, col_f, wgt_f, cur_b, col_b, wgt_b);
  k_init<<<(BN * 13 * 32 + 255) / 256, 256, 0, stream>>>(x, init_w, init_b, hA);

  const int ngrid = (BN + 7) / 8;
#define LAYER(l, LIN, DD, hin, hout) \
  k_tcn<LIN, DD><<<ngrid, 256, 0, stream>>>(hin, tbuf, filt_w + l * 2048, filt_b + l * 32, \
                                            gate_w + l * 2048, gate_b + l * 32); \
  k_agg<LIN - DD, DD><<<ngrid, 256, 0, stream>>>(tbuf, hin, hout, lastcol + l * BN * 32, \
      row_f, col_f, wgt_f, row_b, col_b, wgt_b, gcn_w + l * 6144, gcn_b + l * 32);

  LAYER(0, 13, 1, hA, hB)
  LAYER(1, 12, 2, hB, hA)
  LAYER(2, 10, 1, hA, hB)
  LAYER(3, 9, 2, hB, hA)
  LAYER(4, 7, 1, hA, hB)
  LAYER(5, 6, 2, hB, hA)
  LAYER(6, 4, 1, hA, hB)
  LAYER(7, 3, 2, hB, hA)
#undef LAYER

  k_final<<<(BN + 15) / 16, 256, 0, stream>>>(lastcol, skip_w, skip_b, w0, b0, w1, b1, out);
}

// Round 2
// 1099.353 us; speedup vs baseline: 1.9121x; 1.9121x over previous
//
#include <hip/hip_runtime.h>

#define BN 13248
#define NE 211968

__device__ __forceinline__ float fast_tanh(float x) {
  float e2 = __expf(2.f * x);
  return 1.f - 2.f / (e2 + 1.f);   // inf-safe
}
__device__ __forceinline__ float fast_sig(float x) {
  return 1.f / (1.f + __expf(-x));
}

// ---------------- CSR build ----------------
__global__ void k_count(const int* __restrict__ src, const int* __restrict__ dst,
                        int* __restrict__ cur_f, int* __restrict__ cur_b) {
  int e = blockIdx.x * 256 + threadIdx.x;
  if (e < NE) {
    atomicAdd(&cur_f[dst[e]], 1);
    atomicAdd(&cur_b[src[e]], 1);
  }
}

__global__ void k_scan(int* __restrict__ cur_f, int* __restrict__ row_f,
                       int* __restrict__ cur_b, int* __restrict__ row_b) {
  __shared__ int sdata[1024];
  int tid = threadIdx.x;
  for (int which = 0; which < 2; ++which) {
    int* cnt = which ? cur_b : cur_f;
    int* row = which ? row_b : row_f;
    int base = tid * 13;
    int vals[13];
    int tot = 0;
    for (int k = 0; k < 13; ++k) {
      int idx = base + k;
      int v = (idx < BN) ? cnt[idx] : 0;
      vals[k] = v; tot += v;
    }
    sdata[tid] = tot;
    __syncthreads();
    for (int off = 1; off < 1024; off <<= 1) {
      int add = (tid >= off) ? sdata[tid - off] : 0;
      __syncthreads();
      sdata[tid] += add;
      __syncthreads();
    }
    int running = sdata[tid] - tot;  // exclusive
    for (int k = 0; k < 13; ++k) {
      int idx = base + k;
      if (idx < BN) { row[idx] = running; cnt[idx] = running; running += vals[k]; }
    }
    if (tid == 1023) row[BN] = sdata[1023];
    __syncthreads();
  }
}

__global__ void k_fill(const int* __restrict__ src, const int* __restrict__ dst,
                       const float* __restrict__ w,
                       int* __restrict__ cur_f, int* __restrict__ col_f, float* __restrict__ w_f,
                       int* __restrict__ cur_b, int* __restrict__ col_b, float* __restrict__ w_b) {
  int e = blockIdx.x * 256 + threadIdx.x;
  if (e < NE) {
    int s = src[e], t = dst[e];
    float wv = w[e];
    int p = atomicAdd(&cur_f[t], 1); col_f[p] = s; w_f[p] = wv;
    int q = atomicAdd(&cur_b[s], 1); col_b[q] = t; w_b[q] = wv;
  }
}

// ---------------- init linear ----------------
__global__ void k_init(const float* __restrict__ x, const float* __restrict__ iw,
                       const float* __restrict__ ib, float* __restrict__ h) {
  int idx = blockIdx.x * 256 + threadIdx.x;
  if (idx >= BN * 13 * 32) return;
  int c = idx & 31;
  int r = idx >> 5;          // r = tau*BN + n
  int n = r % BN;
  int tau = r / BN;
  float x0 = x[(n * 13 + tau) * 2 + 0];
  float x1 = x[(n * 13 + tau) * 2 + 1];
  h[idx] = fmaf(x0, iw[c], fmaf(x1, iw[32 + c], ib[c]));
}

// ---------------- gated TCN: writes bf16 t, node-major padded ----------------
template<int LIN, int D, int TPAD>
__global__ __launch_bounds__(256) void k_tcn(const float* __restrict__ h_in, unsigned short* __restrict__ t_out,
    const float* __restrict__ fw, const float* __restrict__ fb,
    const float* __restrict__ gw, const float* __restrict__ gb) {
  constexpr int LOUT = LIN - D;
  __shared__ __align__(16) float wq[32 * 32 * 4];   // [(ci*32+co)*4 + {f0,f1,g0,g1}]
  __shared__ float hl[8][LIN * 32];
  int tid = threadIdx.x;
  for (int f = tid; f < 4096; f += 256) {
    int e = f & 3, co = (f >> 2) & 31, ci = f >> 7;
    const float* srcw = (e < 2) ? fw : gw;
    wq[f] = srcw[(co * 32 + ci) * 2 + (e & 1)];
  }
  int n0 = blockIdx.x * 8;
  for (int i = tid; i < 8 * LIN * 32; i += 256) {
    int c = i & 31, r = i >> 5;
    int nl = r / LIN, tau = r % LIN;
    hl[nl][tau * 32 + c] = h_in[(tau * BN + n0 + nl) * 32 + c];
  }
  __syncthreads();
  int nl = tid >> 5, co = tid & 31;
  int n = n0 + nl;
  float accf[LOUT], accg[LOUT];
  float fbv = fb[co], gbv = gb[co];
#pragma unroll
  for (int j = 0; j < LOUT; ++j) { accf[j] = fbv; accg[j] = gbv; }
#pragma unroll
  for (int ci = 0; ci < 32; ++ci) {
    float4 wv = *(const float4*)&wq[(ci * 32 + co) * 4];
    float xr[LIN];
#pragma unroll
    for (int t = 0; t < LIN; ++t) xr[t] = hl[nl][t * 32 + ci];
#pragma unroll
    for (int j = 0; j < LOUT; ++j) {
      accf[j] = fmaf(xr[j], wv.x, accf[j]);
      accf[j] = fmaf(xr[j + D], wv.y, accf[j]);
      accg[j] = fmaf(xr[j], wv.z, accg[j]);
      accg[j] = fmaf(xr[j + D], wv.w, accg[j]);
    }
  }
#pragma unroll
  for (int j = 0; j < LOUT; ++j) {
    float v = fast_tanh(accf[j]) * fast_sig(accg[j]);
    unsigned bits = __float_as_uint(v);
    unsigned r = (bits + 0x7FFFu + ((bits >> 16) & 1u)) >> 16;   // RNE to bf16
    t_out[(n * TPAD + j) * 32 + co] = (unsigned short)r;
  }
}

// ---------------- diffusion conv ----------------
__device__ __forceinline__ void bf4_fma(uint2 u, float w1, float4* A) {
  float v0 = __uint_as_float(u.x << 16);
  float v1 = __uint_as_float(u.x & 0xFFFF0000u);
  float v2 = __uint_as_float(u.y << 16);
  float v3 = __uint_as_float(u.y & 0xFFFF0000u);
  float w2 = w1 * w1, w3 = w2 * w1;
  A[0].x = fmaf(w1, v0, A[0].x); A[0].y = fmaf(w1, v1, A[0].y);
  A[0].z = fmaf(w1, v2, A[0].z); A[0].w = fmaf(w1, v3, A[0].w);
  A[1].x = fmaf(w2, v0, A[1].x); A[1].y = fmaf(w2, v1, A[1].y);
  A[1].z = fmaf(w2, v2, A[1].z); A[1].w = fmaf(w2, v3, A[1].w);
  A[2].x = fmaf(w3, v0, A[2].x); A[2].y = fmaf(w3, v1, A[2].y);
  A[2].z = fmaf(w3, v2, A[2].z); A[2].w = fmaf(w3, v3, A[2].w);
}

template<int TPAD>
__device__ __forceinline__ void gather_dir(const unsigned short* __restrict__ t_in,
    int e0, int e1, const int* __restrict__ col, const float* __restrict__ warr,
    int lane32, int rowoff, float4* A) {
  for (int base = e0; base < e1; base += 32) {
    int idx = base + lane32;
    int cv = 0; float wv = 0.f;
    if (idx < e1) { cv = col[idx]; wv = warr[idx]; }
    int cnt = min(32, e1 - base);
    int b = 0;
    for (; b + 8 <= cnt; b += 8) {
      uint2 u[8]; float w1[8];
#pragma unroll
      for (int k = 0; k < 8; ++k) {
        int s = __shfl(cv, b + k, 32);
        w1[k] = __shfl(wv, b + k, 32);
        u[k] = *(const uint2*)(t_in + s * (TPAD * 32) + rowoff);
      }
#pragma unroll
      for (int k = 0; k < 8; ++k) bf4_fma(u[k], w1[k], A);
    }
    for (; b < cnt; ++b) {
      int s = __shfl(cv, b, 32);
      float ww = __shfl(wv, b, 32);
      uint2 u = *(const uint2*)(t_in + s * (TPAD * 32) + rowoff);
      bf4_fma(u, ww, A);
    }
  }
}

template<int LOUT, int D, int TPAD>
__global__ __launch_bounds__(256) void k_agg(const unsigned short* __restrict__ t_in,
    const float* __restrict__ h_in, float* __restrict__ h_out, float* __restrict__ lastcol,
    const int* __restrict__ row_f, const int* __restrict__ col_f, const float* __restrict__ w_f,
    const int* __restrict__ row_b, const int* __restrict__ col_b, const float* __restrict__ w_b,
    const float* __restrict__ W, const float* __restrict__ bias) {
  __shared__ __align__(16) float Wt[6 * 32 * 36];        // Wt[a][co][ci], pad 36
  __shared__ __align__(16) float4 zl[8][6][4][8];        // [nl][a][tau_l][c/4]
  int tid = threadIdx.x;
  for (int f = tid; f < 6144; f += 256) {
    int a = f >> 10, ci = (f >> 5) & 31, co = f & 31;
    Wt[a * 1152 + co * 36 + ci] = W[f];
  }
  int nl = tid >> 5, lane32 = tid & 31;
  int tl = lane32 >> 3;              // local tau 0..3 (gather phase)
  int c4 = (lane32 & 7) << 2;        // 4-channel group (gather phase)
  int n = blockIdx.x * 8 + nl;       // BN % 8 == 0
  int tau0 = blockIdx.y * 4;
  int rowoff = (tau0 + tl) * 32 + c4;
  int ef0 = row_f[n], ef1 = row_f[n + 1];
  int eb0 = row_b[n], eb1 = row_b[n + 1];
  float4 acc[6];
#pragma unroll
  for (int a = 0; a < 6; ++a) acc[a] = make_float4(0.f, 0.f, 0.f, 0.f);
  gather_dir<TPAD>(t_in, ef0, ef1, col_f, w_f, lane32, rowoff, acc + 0);
  gather_dir<TPAD>(t_in, eb0, eb1, col_b, w_b, lane32, rowoff, acc + 3);
#pragma unroll
  for (int a = 0; a < 6; ++a) zl[nl][a][tl][lane32 & 7] = acc[a];
  __syncthreads();   // covers Wt (cross-wave); zl is same-wave
  // matmul: g[tau][co=lane32] = sum_a sum_ci z[a][tau][ci] * Wt[a][co][ci]
  float bco = bias[lane32];
  float g[4] = { bco, bco, bco, bco };
#pragma unroll
  for (int a = 0; a < 6; ++a) {
    const float4* wp = (const float4*)&Wt[a * 1152 + lane32 * 36];
    float4 w0 = wp[0], w1v = wp[1], w2v = wp[2], w3v = wp[3];
    float4 w4 = wp[4], w5 = wp[5], w6 = wp[6], w7 = wp[7];
#pragma unroll
    for (int j = 0; j < 4; ++j) {
      if (tau0 + j < LOUT) {
        const float4* zp = &zl[nl][a][j][0];
        float4 z0 = zp[0], z1 = zp[1], z2 = zp[2], z3 = zp[3];
        float4 z4 = zp[4], z5 = zp[5], z6 = zp[6], z7 = zp[7];
        float gg = g[j];
        gg = fmaf(z0.x, w0.x, gg); gg = fmaf(z0.y, w0.y, gg); gg = fmaf(z0.z, w0.z, gg); gg = fmaf(z0.w, w0.w, gg);
        gg = fmaf(z1.x, w1v.x, gg); gg = fmaf(z1.y, w1v.y, gg); gg = fmaf(z1.z, w1v.z, gg); gg = fmaf(z1.w, w1v.w, gg);
        gg = fmaf(z2.x, w2v.x, gg); gg = fmaf(z2.y, w2v.y, gg); gg = fmaf(z2.z, w2v.z, gg); gg = fmaf(z2.w, w2v.w, gg);
        gg = fmaf(z3.x, w3v.x, gg); gg = fmaf(z3.y, w3v.y, gg); gg = fmaf(z3.z, w3v.z, gg); gg = fmaf(z3.w, w3v.w, gg);
        gg = fmaf(z4.x, w4.x, gg); gg = fmaf(z4.y, w4.y, gg); gg = fmaf(z4.z, w4.z, gg); gg = fmaf(z4.w, w4.w, gg);
        gg = fmaf(z5.x, w5.x, gg); gg = fmaf(z5.y, w5.y, gg); gg = fmaf(z5.z, w5.z, gg); gg = fmaf(z5.w, w5.w, gg);
        gg = fmaf(z6.x, w6.x, gg); gg = fmaf(z6.y, w6.y, gg); gg = fmaf(z6.z, w6.z, gg); gg = fmaf(z6.w, w6.w, gg);
        gg = fmaf(z7.x, w7.x, gg); gg = fmaf(z7.y, w7.y, gg); gg = fmaf(z7.z, w7.z, gg); gg = fmaf(z7.w, w7.w, gg);
        g[j] = gg;
      }
    }
  }
#pragma unroll
  for (int j = 0; j < 4; ++j) {
    int tau = tau0 + j;
    if (tau < LOUT) {
      float r = h_in[((tau + D) * BN + n) * 32 + lane32];   // residual
      float o = g[j] + r;
      h_out[(tau * BN + n) * 32 + lane32] = o;
      if (tau == LOUT - 1) lastcol[n * 32 + lane32] = o;
    }
  }
}

// ------------- fused head -------------
__global__ __launch_bounds__(256) void k_final(const float* __restrict__ lastcol,
    const float* __restrict__ skip_w, const float* __restrict__ skip_b,
    const float* __restrict__ w0, const float* __restrict__ b0,
    const float* __restrict__ w1, const float* __restrict__ b1,
    float* __restrict__ out) {
  __shared__ float z[16 * 256];
  __shared__ float ws[32 * 257];
  int tid = threadIdx.x;
  int n0 = blockIdx.x * 16;
  {
    int l = tid >> 5, c = tid & 31;
    for (int k = 0; k < 16; ++k) {
      int n = n0 + k;
      z[k * 256 + tid] = lastcol[(l * BN + n) * 32 + c];
    }
  }
  __syncthreads();
  float acc[16];
#pragma unroll
  for (int k = 0; k < 16; ++k) acc[k] = 0.f;
  for (int ll = 0; ll < 8; ++ll) {
    __syncthreads();
    for (int f = tid; f < 8192; f += 256) {
      int cc = f & 31, jj = f >> 5;
      ws[cc * 257 + jj] = skip_w[(ll * 256 + jj) * 32 + cc];
    }
    __syncthreads();
#pragma unroll
    for (int k = 0; k < 16; ++k) {
      float a = acc[k];
#pragma unroll
      for (int cc = 0; cc < 32; ++cc)
        a = fmaf(z[k * 256 + ll * 32 + cc], ws[cc * 257 + tid], a);
      acc[k] = a;
    }
  }
  float bsum = 0.f;
  for (int ll = 0; ll < 8; ++ll) bsum += skip_b[ll * 256 + tid];
  __syncthreads();
#pragma unroll
  for (int k = 0; k < 16; ++k) z[k * 256 + tid] = fmaxf(acc[k] + bsum, 0.f);
  __syncthreads();
  float h0a[16], h1a[16];
  float b0v0 = b0[tid], b0v1 = b0[tid + 256];
#pragma unroll
  for (int k = 0; k < 16; ++k) { h0a[k] = b0v0; h1a[k] = b0v1; }
  for (int j = 0; j < 256; ++j) {
    float wv0 = w0[j * 512 + tid];
    float wv1 = w0[j * 512 + tid + 256];
#pragma unroll
    for (int k = 0; k < 16; ++k) {
      float sv = z[k * 256 + j];
      h0a[k] = fmaf(sv, wv0, h0a[k]);
      h1a[k] = fmaf(sv, wv1, h1a[k]);
    }
  }
  __syncthreads();
#pragma unroll
  for (int k = 0; k < 16; ++k) {
    ws[k * 514 + tid] = fmaxf(h0a[k], 0.f);
    ws[k * 514 + tid + 256] = fmaxf(h1a[k], 0.f);
  }
  __syncthreads();
  if (tid < 192) {
    int k = tid / 12, j = tid % 12;
    int n = n0 + k;
    float a = b1[j];
    for (int t = 0; t < 512; ++t)
      a = fmaf(ws[k * 514 + t], w1[t * 12 + j], a);
    out[n * 12 + j] = a;
  }
}

extern "C" void kernel_launch(void* const* d_in, const int* in_sizes, int n_in,
                              void* d_out, int out_size, void* d_ws, size_t ws_size,
                              hipStream_t stream) {
  const float* x      = (const float*)d_in[0];
  const int*   esrc   = (const int*)d_in[1];
  const int*   edst   = (const int*)d_in[2];
  const float* ew     = (const float*)d_in[3];
  const float* init_w = (const float*)d_in[4];
  const float* init_b = (const float*)d_in[5];
  const float* filt_w = (const float*)d_in[6];
  const float* filt_b = (const float*)d_in[7];
  const float* gate_w = (const float*)d_in[8];
  const float* gate_b = (const float*)d_in[9];
  const float* gcn_w  = (const float*)d_in[10];
  const float* gcn_b  = (const float*)d_in[11];
  const float* skip_w = (const float*)d_in[12];
  const float* skip_b = (const float*)d_in[13];
  const float* w0     = (const float*)d_in[14];
  const float* b0     = (const float*)d_in[15];
  const float* w1     = (const float*)d_in[16];
  const float* b1     = (const float*)d_in[17];
  float* out = (float*)d_out;

  float* base = (float*)d_ws;
  float* hA      = base;                       // 13*BN*32 f32
  float* hB      = hA + 13 * BN * 32;          // 13*BN*32 f32
  float* tbuf    = hB + 13 * BN * 32;          // 12*BN*32 region (used as bf16)
  float* lastcol = tbuf + 12 * BN * 32;        // 8*BN*32 f32
  int* row_f = (int*)(lastcol + 8 * BN * 32);  // BN+1
  int* row_b = row_f + (BN + 1);               // BN+1
  int* cur_f = row_b + (BN + 1);               // BN
  int* cur_b = cur_f + BN;                     // BN
  int* col_f = cur_b + BN;                     // NE
  int* col_b = col_f + NE;                     // NE
  float* wgt_f = (float*)(col_b + NE);         // NE
  float* wgt_b = wgt_f + NE;                   // NE
  unsigned short* tbuf_u = (unsigned short*)tbuf;

  hipMemsetAsync(cur_f, 0, 2 * BN * sizeof(int), stream);
  const int egrid = (NE + 255) / 256;
  k_count<<<egrid, 256, 0, stream>>>(esrc, edst, cur_f, cur_b);
  k_scan<<<1, 1024, 0, stream>>>(cur_f, row_f, cur_b, row_b);
  k_fill<<<egrid, 256, 0, stream>>>(esrc, edst, ew, cur_f, col_f, wgt_f, cur_b, col_b, wgt_b);
  k_init<<<(BN * 13 * 32 + 255) / 256, 256, 0, stream>>>(x, init_w, init_b, hA);

  const int ngrid = BN / 8;
#define LAYER(l, LIN, DD, TP, hin, hout) \
  k_tcn<LIN, DD, TP><<<ngrid, 256, 0, stream>>>(hin, tbuf_u, filt_w + l * 2048, filt_b + l * 32, \
                                                gate_w + l * 2048, gate_b + l * 32); \
  k_agg<LIN - DD, DD, TP><<<dim3(ngrid, ((LIN - DD) + 3) / 4), 256, 0, stream>>>(tbuf_u, hin, hout, \
      lastcol + l * BN * 32, row_f, col_f, wgt_f, row_b, col_b, wgt_b, gcn_w + l * 6144, gcn_b + l * 32);

  LAYER(0, 13, 1, 12, hA, hB)
  LAYER(1, 12, 2, 12, hB, hA)
  LAYER(2, 10, 1, 12, hA, hB)
  LAYER(3,  9, 2, 12, hB, hA)
  LAYER(4,  7, 1,  8, hA, hB)
  LAYER(5,  6, 2,  8, hB, hA)
  LAYER(6,  4, 1,  4, hA, hB)
  LAYER(7,  3, 2,  4, hB, hA)
#undef LAYER

  k_final<<<BN / 16, 256, 0, stream>>>(lastcol, skip_w, skip_b, w0, b0, w1, b1, out);
}

// Round 3
// 959.683 us; speedup vs baseline: 2.1904x; 1.1455x over previous
//
#include <hip/hip_runtime.h>

#define BN 13248
#define NE 211968

typedef __attribute__((ext_vector_type(8))) short bf16x8;
typedef __attribute__((ext_vector_type(4))) float f32x4;

__device__ __forceinline__ f32x4 mfma16(bf16x8 a, bf16x8 b, f32x4 c) {
  return __builtin_amdgcn_mfma_f32_16x16x32_bf16(a, b, c, 0, 0, 0);
}

__device__ __forceinline__ unsigned short to_bf16(float v) {
  unsigned bits = __float_as_uint(v);
  return (unsigned short)((bits + 0x7FFFu + ((bits >> 16) & 1u)) >> 16);   // RNE
}

__device__ __forceinline__ float fast_tanh(float x) {
  float e2 = __expf(2.f * x);
  return 1.f - 2.f / (e2 + 1.f);   // inf-safe
}
__device__ __forceinline__ float fast_sig(float x) {
  return 1.f / (1.f + __expf(-x));
}

// ---------------- CSR build ----------------
__global__ void k_count(const int* __restrict__ src, const int* __restrict__ dst,
                        int* __restrict__ cur_f, int* __restrict__ cur_b) {
  int e = blockIdx.x * 256 + threadIdx.x;
  if (e < NE) {
    atomicAdd(&cur_f[dst[e]], 1);
    atomicAdd(&cur_b[src[e]], 1);
  }
}

__global__ void k_scan(int* __restrict__ cur_f, int* __restrict__ row_f,
                       int* __restrict__ cur_b, int* __restrict__ row_b) {
  __shared__ int sdata[1024];
  int tid = threadIdx.x;
  for (int which = 0; which < 2; ++which) {
    int* cnt = which ? cur_b : cur_f;
    int* row = which ? row_b : row_f;
    int base = tid * 13;
    int vals[13];
    int tot = 0;
    for (int k = 0; k < 13; ++k) {
      int idx = base + k;
      int v = (idx < BN) ? cnt[idx] : 0;
      vals[k] = v; tot += v;
    }
    sdata[tid] = tot;
    __syncthreads();
    for (int off = 1; off < 1024; off <<= 1) {
      int add = (tid >= off) ? sdata[tid - off] : 0;
      __syncthreads();
      sdata[tid] += add;
      __syncthreads();
    }
    int running = sdata[tid] - tot;  // exclusive
    for (int k = 0; k < 13; ++k) {
      int idx = base + k;
      if (idx < BN) { row[idx] = running; cnt[idx] = running; running += vals[k]; }
    }
    if (tid == 1023) row[BN] = sdata[1023];
    __syncthreads();
  }
}

__global__ void k_fill(const int* __restrict__ src, const int* __restrict__ dst,
                       const float* __restrict__ w,
                       int* __restrict__ cur_f, int* __restrict__ col_f, float* __restrict__ w_f,
                       int* __restrict__ cur_b, int* __restrict__ col_b, float* __restrict__ w_b) {
  int e = blockIdx.x * 256 + threadIdx.x;
  if (e < NE) {
    int s = src[e], t = dst[e];
    float wv = w[e];
    int p = atomicAdd(&cur_f[t], 1); col_f[p] = s; w_f[p] = wv;
    int q = atomicAdd(&cur_b[s], 1); col_b[q] = t; w_b[q] = wv;
  }
}

// ---------------- init linear ----------------
__global__ void k_init(const float* __restrict__ x, const float* __restrict__ iw,
                       const float* __restrict__ ib, float* __restrict__ h) {
  int idx = blockIdx.x * 256 + threadIdx.x;
  if (idx >= BN * 13 * 32) return;
  int c = idx & 31;
  int r = idx >> 5;          // r = tau*BN + n
  int n = r % BN;
  int tau = r / BN;
  float x0 = x[(n * 13 + tau) * 2 + 0];
  float x1 = x[(n * 13 + tau) * 2 + 1];
  h[idx] = fmaf(x0, iw[c], fmaf(x1, iw[32 + c], ib[c]));
}

// ---------------- weight pre-pack for MFMA head ----------------
__global__ void k_pack(const float* __restrict__ skip_w, const float* __restrict__ skip_b,
                       const float* __restrict__ w0, const float* __restrict__ w1,
                       unsigned short* __restrict__ SWb, unsigned short* __restrict__ W0T,
                       unsigned short* __restrict__ W1T, float* __restrict__ bsum) {
  int id = blockIdx.x * 256 + threadIdx.x;
  if (id < 65536) {          // SWb[j][k=l*32+c] = skip_w[l][j][c]
    int j = id >> 8, k = id & 255;
    SWb[id] = to_bf16(skip_w[((k >> 5) * 256 + j) * 32 + (k & 31)]);
  }
  if (id < 131072) {         // W0T[jo][k] = w0[k][jo]
    int jo = id >> 8, k = id & 255;
    W0T[id] = to_bf16(w0[k * 512 + jo]);
  }
  if (id < 8192) {           // W1T[n][k] = w1[k][n], n padded to 16
    int n = id >> 9, k = id & 511;
    W1T[id] = (n < 12) ? to_bf16(w1[k * 12 + n]) : (unsigned short)0;
  }
  if (id < 256) {
    float s = 0.f;
    for (int l = 0; l < 8; ++l) s += skip_b[l * 256 + id];
    bsum[id] = s;
  }
}

// ---------------- gated TCN: writes bf16 t, node-major padded ----------------
template<int LIN, int D, int TPAD>
__global__ __launch_bounds__(256) void k_tcn(const float* __restrict__ h_in, unsigned short* __restrict__ t_out,
    const float* __restrict__ fw, const float* __restrict__ fb,
    const float* __restrict__ gw, const float* __restrict__ gb) {
  constexpr int LOUT = LIN - D;
  __shared__ __align__(16) float wq[32 * 32 * 4];   // [(ci*32+co)*4 + {f0,f1,g0,g1}]
  __shared__ float hl[8][LIN * 32];
  int tid = threadIdx.x;
  for (int f = tid; f < 4096; f += 256) {
    int e = f & 3, co = (f >> 2) & 31, ci = f >> 7;
    const float* srcw = (e < 2) ? fw : gw;
    wq[f] = srcw[(co * 32 + ci) * 2 + (e & 1)];
  }
  int n0 = blockIdx.x * 8;
  for (int i = tid; i < 8 * LIN * 32; i += 256) {
    int c = i & 31, r = i >> 5;
    int nl = r / LIN, tau = r % LIN;
    hl[nl][tau * 32 + c] = h_in[(tau * BN + n0 + nl) * 32 + c];
  }
  __syncthreads();
  int nl = tid >> 5, co = tid & 31;
  int n = n0 + nl;
  float accf[LOUT], accg[LOUT];
  float fbv = fb[co], gbv = gb[co];
#pragma unroll
  for (int j = 0; j < LOUT; ++j) { accf[j] = fbv; accg[j] = gbv; }
#pragma unroll
  for (int ci = 0; ci < 32; ++ci) {
    float4 wv = *(const float4*)&wq[(ci * 32 + co) * 4];
    float xr[LIN];
#pragma unroll
    for (int t = 0; t < LIN; ++t) xr[t] = hl[nl][t * 32 + ci];
#pragma unroll
    for (int j = 0; j < LOUT; ++j) {
      accf[j] = fmaf(xr[j], wv.x, accf[j]);
      accf[j] = fmaf(xr[j + D], wv.y, accf[j]);
      accg[j] = fmaf(xr[j], wv.z, accg[j]);
      accg[j] = fmaf(xr[j + D], wv.w, accg[j]);
    }
  }
#pragma unroll
  for (int j = 0; j < LOUT; ++j) {
    float v = fast_tanh(accf[j]) * fast_sig(accg[j]);
    t_out[(n * TPAD + j) * 32 + co] = to_bf16(v);
  }
}

// ---------------- diffusion conv ----------------
__device__ __forceinline__ void bf4_fma(uint2 u, float w1, float4* A) {
  float v0 = __uint_as_float(u.x << 16);
  float v1 = __uint_as_float(u.x & 0xFFFF0000u);
  float v2 = __uint_as_float(u.y << 16);
  float v3 = __uint_as_float(u.y & 0xFFFF0000u);
  float w2 = w1 * w1, w3 = w2 * w1;
  A[0].x = fmaf(w1, v0, A[0].x); A[0].y = fmaf(w1, v1, A[0].y);
  A[0].z = fmaf(w1, v2, A[0].z); A[0].w = fmaf(w1, v3, A[0].w);
  A[1].x = fmaf(w2, v0, A[1].x); A[1].y = fmaf(w2, v1, A[1].y);
  A[1].z = fmaf(w2, v2, A[1].z); A[1].w = fmaf(w2, v3, A[1].w);
  A[2].x = fmaf(w3, v0, A[2].x); A[2].y = fmaf(w3, v1, A[2].y);
  A[2].z = fmaf(w3, v2, A[2].z); A[2].w = fmaf(w3, v3, A[2].w);
}

template<int TPAD>
__device__ __forceinline__ void gather_dir(const unsigned short* __restrict__ t_in,
    int e0, int e1, const int* __restrict__ col, const float* __restrict__ warr,
    int lane32, int rowoff, float4* A) {
  for (int base = e0; base < e1; base += 32) {
    int idx = base + lane32;
    int cv = 0; float wv = 0.f;
    if (idx < e1) { cv = col[idx]; wv = warr[idx]; }
    int cnt = min(32, e1 - base);
    int b = 0;
    for (; b + 8 <= cnt; b += 8) {
      uint2 u[8]; float w1[8];
#pragma unroll
      for (int k = 0; k < 8; ++k) {
        int s = __shfl(cv, b + k, 32);
        w1[k] = __shfl(wv, b + k, 32);
        u[k] = *(const uint2*)(t_in + s * (TPAD * 32) + rowoff);
      }
#pragma unroll
      for (int k = 0; k < 8; ++k) bf4_fma(u[k], w1[k], A);
    }
    for (; b < cnt; ++b) {
      int s = __shfl(cv, b, 32);
      float ww = __shfl(wv, b, 32);
      uint2 u = *(const uint2*)(t_in + s * (TPAD * 32) + rowoff);
      bf4_fma(u, ww, A);
    }
  }
}

template<int LOUT, int D, int TPAD>
__global__ __launch_bounds__(256) void k_agg(const unsigned short* __restrict__ t_in,
    const float* __restrict__ h_in, float* __restrict__ h_out, float* __restrict__ lastcol,
    const int* __restrict__ row_f, const int* __restrict__ col_f, const float* __restrict__ w_f,
    const int* __restrict__ row_b, const int* __restrict__ col_b, const float* __restrict__ w_b,
    const float* __restrict__ W, const float* __restrict__ bias) {
  __shared__ __align__(16) float Wt[6 * 32 * 36];        // Wt[a][co][ci], pad 36
  __shared__ __align__(16) float4 zl[8][6][4][8];        // [nl][a][tau_l][c/4]
  int tid = threadIdx.x;
  for (int f = tid; f < 6144; f += 256) {
    int a = f >> 10, ci = (f >> 5) & 31, co = f & 31;
    Wt[a * 1152 + co * 36 + ci] = W[f];
  }
  int nl = tid >> 5, lane32 = tid & 31;
  int tl = lane32 >> 3;              // local tau 0..3 (gather phase)
  int c4 = (lane32 & 7) << 2;        // 4-channel group (gather phase)
  int n = blockIdx.x * 8 + nl;       // BN % 8 == 0
  int tau0 = blockIdx.y * 4;
  int rowoff = (tau0 + tl) * 32 + c4;
  int ef0 = row_f[n], ef1 = row_f[n + 1];
  int eb0 = row_b[n], eb1 = row_b[n + 1];
  float4 acc[6];
#pragma unroll
  for (int a = 0; a < 6; ++a) acc[a] = make_float4(0.f, 0.f, 0.f, 0.f);
  gather_dir<TPAD>(t_in, ef0, ef1, col_f, w_f, lane32, rowoff, acc + 0);
  gather_dir<TPAD>(t_in, eb0, eb1, col_b, w_b, lane32, rowoff, acc + 3);
#pragma unroll
  for (int a = 0; a < 6; ++a) zl[nl][a][tl][lane32 & 7] = acc[a];
  __syncthreads();   // covers Wt (cross-wave); zl is same-wave
  float bco = bias[lane32];
  float g[4] = { bco, bco, bco, bco };
#pragma unroll
  for (int a = 0; a < 6; ++a) {
    const float4* wp = (const float4*)&Wt[a * 1152 + lane32 * 36];
    float4 w0 = wp[0], w1v = wp[1], w2v = wp[2], w3v = wp[3];
    float4 w4 = wp[4], w5 = wp[5], w6 = wp[6], w7 = wp[7];
#pragma unroll
    for (int j = 0; j < 4; ++j) {
      if (tau0 + j < LOUT) {
        const float4* zp = &zl[nl][a][j][0];
        float4 z0 = zp[0], z1 = zp[1], z2 = zp[2], z3 = zp[3];
        float4 z4 = zp[4], z5 = zp[5], z6 = zp[6], z7 = zp[7];
        float gg = g[j];
        gg = fmaf(z0.x, w0.x, gg); gg = fmaf(z0.y, w0.y, gg); gg = fmaf(z0.z, w0.z, gg); gg = fmaf(z0.w, w0.w, gg);
        gg = fmaf(z1.x, w1v.x, gg); gg = fmaf(z1.y, w1v.y, gg); gg = fmaf(z1.z, w1v.z, gg); gg = fmaf(z1.w, w1v.w, gg);
        gg = fmaf(z2.x, w2v.x, gg); gg = fmaf(z2.y, w2v.y, gg); gg = fmaf(z2.z, w2v.z, gg); gg = fmaf(z2.w, w2v.w, gg);
        gg = fmaf(z3.x, w3v.x, gg); gg = fmaf(z3.y, w3v.y, gg); gg = fmaf(z3.z, w3v.z, gg); gg = fmaf(z3.w, w3v.w, gg);
        gg = fmaf(z4.x, w4.x, gg); gg = fmaf(z4.y, w4.y, gg); gg = fmaf(z4.z, w4.z, gg); gg = fmaf(z4.w, w4.w, gg);
        gg = fmaf(z5.x, w5.x, gg); gg = fmaf(z5.y, w5.y, gg); gg = fmaf(z5.z, w5.z, gg); gg = fmaf(z5.w, w5.w, gg);
        gg = fmaf(z6.x, w6.x, gg); gg = fmaf(z6.y, w6.y, gg); gg = fmaf(z6.z, w6.z, gg); gg = fmaf(z6.w, w6.w, gg);
        gg = fmaf(z7.x, w7.x, gg); gg = fmaf(z7.y, w7.y, gg); gg = fmaf(z7.z, w7.z, gg); gg = fmaf(z7.w, w7.w, gg);
        g[j] = gg;
      }
    }
  }
#pragma unroll
  for (int j = 0; j < 4; ++j) {
    int tau = tau0 + j;
    if (tau < LOUT) {
      float r = h_in[((tau + D) * BN + n) * 32 + lane32];   // residual
      float o = g[j] + r;
      h_out[(tau * BN + n) * 32 + lane32] = o;
      if (tau == LOUT - 1) lastcol[n * 32 + lane32] = o;
    }
  }
}

// ------------- fused MFMA head: skip GEMM -> relu -> 256x512 -> relu -> 512x12 -------------
// A-frag: lane holds A[m=lane&15][k=(lane>>4)*8+j]  (learn_hip m120)
// B-frag from B^T rows: lane holds B[k=(lane>>4)*8+j][n=lane&15]  (m92/m97 pattern)
// C/D:    col=lane&15, row=(lane>>4)*4+reg          (m89/m91)
__device__ __forceinline__ bf16x8 ldsA(const unsigned short* buf, int stride, int row, int ks, int q) {
  int unit = ks * 4 + q;
  int addr = row * stride + ((unit ^ (row & 7)) << 3);
  return *(const bf16x8*)(buf + addr);
}

__global__ __launch_bounds__(256) void k_final(const float* __restrict__ lastcol,
    const unsigned short* __restrict__ SWb, const unsigned short* __restrict__ W0T,
    const unsigned short* __restrict__ W1T, const float* __restrict__ bsum,
    const float* __restrict__ b0, const float* __restrict__ b1,
    float* __restrict__ out) {
  __shared__ __align__(16) unsigned short Z[32 * 256];   // GEMM1 A, then relu(skip) (GEMM2 A)
  __shared__ __align__(16) unsigned short H[32 * 512];   // GEMM3 A
  int tid = threadIdx.x;
  int wave = tid >> 6, lane = tid & 63;
  int m16 = lane & 15, q = lane >> 4;
  int n0 = blockIdx.x * 32;
  // Stage Z: Z[m][k=l*32+c] = bf16(lastcol[l][n0+m][c]), XOR-swizzled in 8-half units
#pragma unroll
  for (int it = 0; it < 32; ++it) {
    int id = it * 256 + tid;
    int m = id >> 8, k = id & 255;
    float v = lastcol[((k >> 5) * BN + n0 + m) * 32 + (k & 31)];
    Z[m * 256 + (((k >> 3) ^ (m & 7)) << 3) + (k & 7)] = to_bf16(v);
  }
  __syncthreads();
  // GEMM1: S[32][256] = Z @ SWb^T ; wave handles 4 N-tiles
  f32x4 acc1[2][4];
#pragma unroll
  for (int mt = 0; mt < 2; ++mt)
#pragma unroll
    for (int i = 0; i < 4; ++i) acc1[mt][i] = (f32x4){0.f, 0.f, 0.f, 0.f};
#pragma unroll
  for (int ks = 0; ks < 8; ++ks) {
    bf16x8 a0 = ldsA(Z, 256, m16, ks, q);
    bf16x8 a1 = ldsA(Z, 256, 16 + m16, ks, q);
#pragma unroll
    for (int i = 0; i < 4; ++i) {
      int j = (wave * 4 + i) * 16 + m16;
      bf16x8 b = *(const bf16x8*)(SWb + j * 256 + ks * 32 + q * 8);
      acc1[0][i] = mfma16(a0, b, acc1[0][i]);
      acc1[1][i] = mfma16(a1, b, acc1[1][i]);
    }
  }
  __syncthreads();   // everyone done reading Z; reuse it for relu(skip)
#pragma unroll
  for (int i = 0; i < 4; ++i) {
    int j = (wave * 4 + i) * 16 + m16;
    float bs = bsum[j];
#pragma unroll
    for (int mt = 0; mt < 2; ++mt)
#pragma unroll
      for (int r = 0; r < 4; ++r) {
        int row = mt * 16 + q * 4 + r;
        float v = fmaxf(acc1[mt][i][r] + bs, 0.f);
        Z[row * 256 + (((j >> 3) ^ (row & 7)) << 3) + (j & 7)] = to_bf16(v);
      }
  }
  __syncthreads();
  // GEMM2: H[32][512] = relu(S) @ W0 ; wave handles 8 N-tiles
  f32x4 acc2[2][8];
#pragma unroll
  for (int mt = 0; mt < 2; ++mt)
#pragma unroll
    for (int i = 0; i < 8; ++i) acc2[mt][i] = (f32x4){0.f, 0.f, 0.f, 0.f};
#pragma unroll
  for (int ks = 0; ks < 8; ++ks) {
    bf16x8 a0 = ldsA(Z, 256, m16, ks, q);
    bf16x8 a1 = ldsA(Z, 256, 16 + m16, ks, q);
#pragma unroll
    for (int i = 0; i < 8; ++i) {
      int jo = (wave * 8 + i) * 16 + m16;
      bf16x8 b = *(const bf16x8*)(W0T + jo * 256 + ks * 32 + q * 8);
      acc2[0][i] = mfma16(a0, b, acc2[0][i]);
      acc2[1][i] = mfma16(a1, b, acc2[1][i]);
    }
  }
#pragma unroll
  for (int i = 0; i < 8; ++i) {
    int jo = (wave * 8 + i) * 16 + m16;
    float b0v = b0[jo];
#pragma unroll
    for (int mt = 0; mt < 2; ++mt)
#pragma unroll
      for (int r = 0; r < 4; ++r) {
        int row = mt * 16 + q * 4 + r;
        float v = fmaxf(acc2[mt][i][r] + b0v, 0.f);
        H[row * 512 + (((jo >> 3) ^ (row & 7)) << 3) + (jo & 7)] = to_bf16(v);
      }
  }
  __syncthreads();
  // GEMM3: out[32][12] = relu(H) @ W1 ; waves 0,1 (one M-tile each), N padded to 16
  if (wave < 2) {
    f32x4 acc3 = (f32x4){0.f, 0.f, 0.f, 0.f};
#pragma unroll
    for (int ks = 0; ks < 16; ++ks) {
      bf16x8 a = ldsA(H, 512, wave * 16 + m16, ks, q);
      bf16x8 b = *(const bf16x8*)(W1T + m16 * 512 + ks * 32 + q * 8);
      acc3 = mfma16(a, b, acc3);
    }
    if (m16 < 12) {
      float bv = b1[m16];
#pragma unroll
      for (int r = 0; r < 4; ++r)
        out[(n0 + wave * 16 + q * 4 + r) * 12 + m16] = acc3[r] + bv;
    }
  }
}

extern "C" void kernel_launch(void* const* d_in, const int* in_sizes, int n_in,
                              void* d_out, int out_size, void* d_ws, size_t ws_size,
                              hipStream_t stream) {
  const float* x      = (const float*)d_in[0];
  const int*   esrc   = (const int*)d_in[1];
  const int*   edst   = (const int*)d_in[2];
  const float* ew     = (const float*)d_in[3];
  const float* init_w = (const float*)d_in[4];
  const float* init_b = (const float*)d_in[5];
  const float* filt_w = (const float*)d_in[6];
  const float* filt_b = (const float*)d_in[7];
  const float* gate_w = (const float*)d_in[8];
  const float* gate_b = (const float*)d_in[9];
  const float* gcn_w  = (const float*)d_in[10];
  const float* gcn_b  = (const float*)d_in[11];
  const float* skip_w = (const float*)d_in[12];
  const float* skip_b = (const float*)d_in[13];
  const float* w0     = (const float*)d_in[14];
  const float* b0     = (const float*)d_in[15];
  const float* w1     = (const float*)d_in[16];
  const float* b1     = (const float*)d_in[17];
  float* out = (float*)d_out;

  float* base = (float*)d_ws;
  float* hA      = base;                       // 13*BN*32 f32
  float* hB      = hA + 13 * BN * 32;          // 13*BN*32 f32
  float* tbuf    = hB + 13 * BN * 32;          // 12*BN*32 f32 region (used as bf16, TP<=12)
  float* lastcol = tbuf + 12 * BN * 32;        // 8*BN*32 f32
  int* row_f = (int*)(lastcol + 8 * BN * 32);  // BN+1
  int* row_b = row_f + (BN + 1);               // BN+1
  int* cur_f = row_b + (BN + 1);               // BN
  int* cur_b = cur_f + BN;                     // BN
  int* col_f = cur_b + BN;                     // NE
  int* col_b = col_f + NE;                     // NE
  float* wgt_f = (float*)(col_b + NE);         // NE
  float* wgt_b = wgt_f + NE;                   // NE
  unsigned short* tbuf_u = (unsigned short*)tbuf;
  // carve bf16 packed weights out of tbuf's unused upper half (TP max = 12 -> 12*BN*32 halves used,
  // region holds 24*BN*32 halves)
  unsigned short* SWb = tbuf_u + 16 * BN * 32;   // 65536 halves
  unsigned short* W0T = SWb + 65536;             // 131072 halves
  unsigned short* W1T = W0T + 131072;            // 8192 halves
  float* bsumv = (float*)(W1T + 8192);           // 256 f32

  hipMemsetAsync(cur_f, 0, 2 * BN * sizeof(int), stream);
  const int egrid = (NE + 255) / 256;
  k_count<<<egrid, 256, 0, stream>>>(esrc, edst, cur_f, cur_b);
  k_scan<<<1, 1024, 0, stream>>>(cur_f, row_f, cur_b, row_b);
  k_fill<<<egrid, 256, 0, stream>>>(esrc, edst, ew, cur_f, col_f, wgt_f, cur_b, col_b, wgt_b);
  k_init<<<(BN * 13 * 32 + 255) / 256, 256, 0, stream>>>(x, init_w, init_b, hA);
  k_pack<<<512, 256, 0, stream>>>(skip_w, skip_b, w0, w1, SWb, W0T, W1T, bsumv);

  const int ngrid = BN / 8;
#define LAYER(l, LIN, DD, TP, hin, hout) \
  k_tcn<LIN, DD, TP><<<ngrid, 256, 0, stream>>>(hin, tbuf_u, filt_w + l * 2048, filt_b + l * 32, \
                                                gate_w + l * 2048, gate_b + l * 32); \
  k_agg<LIN - DD, DD, TP><<<dim3(ngrid, ((LIN - DD) + 3) / 4), 256, 0, stream>>>(tbuf_u, hin, hout, \
      lastcol + l * BN * 32, row_f, col_f, wgt_f, row_b, col_b, wgt_b, gcn_w + l * 6144, gcn_b + l * 32);

  LAYER(0, 13, 1, 12, hA, hB)
  LAYER(1, 12, 2, 12, hB, hA)
  LAYER(2, 10, 1, 12, hA, hB)
  LAYER(3,  9, 2, 12, hB, hA)
  LAYER(4,  7, 1,  8, hA, hB)
  LAYER(5,  6, 2,  8, hB, hA)
  LAYER(6,  4, 1,  4, hA, hB)
  LAYER(7,  3, 2,  4, hB, hA)
#undef LAYER

  k_final<<<BN / 32, 256, 0, stream>>>(lastcol, SWb, W0T, W1T, bsumv, b0, b1, out);
}

// Round 4
// 762.155 us; speedup vs baseline: 2.7581x; 1.2592x over previous
//
#include <hip/hip_runtime.h>

#define BN 13248
#define NE 211968

typedef __attribute__((ext_vector_type(8))) short bf16x8;
typedef __attribute__((ext_vector_type(4))) float f32x4;

__device__ __forceinline__ f32x4 mfma16(bf16x8 a, bf16x8 b, f32x4 c) {
  return __builtin_amdgcn_mfma_f32_16x16x32_bf16(a, b, c, 0, 0, 0);
}

__device__ __forceinline__ unsigned short to_bf16(float v) {
  unsigned bits = __float_as_uint(v);
  return (unsigned short)((bits + 0x7FFFu + ((bits >> 16) & 1u)) >> 16);   // RNE
}

__device__ __forceinline__ float fast_tanh(float x) {
  float e2 = __expf(2.f * x);
  return 1.f - 2.f / (e2 + 1.f);   // inf-safe
}
__device__ __forceinline__ float fast_sig(float x) {
  return 1.f / (1.f + __expf(-x));
}

// ---------------- CSR build ----------------
__global__ void k_count(const int* __restrict__ src, const int* __restrict__ dst,
                        int* __restrict__ cur_f, int* __restrict__ cur_b) {
  int e = blockIdx.x * 256 + threadIdx.x;
  if (e < NE) {
    atomicAdd(&cur_f[dst[e]], 1);
    atomicAdd(&cur_b[src[e]], 1);
  }
}

__global__ void k_scan(int* __restrict__ cur_f, int* __restrict__ row_f,
                       int* __restrict__ cur_b, int* __restrict__ row_b) {
  __shared__ int sdata[1024];
  int tid = threadIdx.x;
  for (int which = 0; which < 2; ++which) {
    int* cnt = which ? cur_b : cur_f;
    int* row = which ? row_b : row_f;
    int base = tid * 13;
    int vals[13];
    int tot = 0;
    for (int k = 0; k < 13; ++k) {
      int idx = base + k;
      int v = (idx < BN) ? cnt[idx] : 0;
      vals[k] = v; tot += v;
    }
    sdata[tid] = tot;
    __syncthreads();
    for (int off = 1; off < 1024; off <<= 1) {
      int add = (tid >= off) ? sdata[tid - off] : 0;
      __syncthreads();
      sdata[tid] += add;
      __syncthreads();
    }
    int running = sdata[tid] - tot;  // exclusive
    for (int k = 0; k < 13; ++k) {
      int idx = base + k;
      if (idx < BN) { row[idx] = running; cnt[idx] = running; running += vals[k]; }
    }
    if (tid == 1023) row[BN] = sdata[1023];
    __syncthreads();
  }
}

__global__ void k_fill(const int* __restrict__ src, const int* __restrict__ dst,
                       const float* __restrict__ w,
                       int* __restrict__ cur_f, int* __restrict__ col_f, float* __restrict__ w_f,
                       int* __restrict__ cur_b, int* __restrict__ col_b, float* __restrict__ w_b) {
  int e = blockIdx.x * 256 + threadIdx.x;
  if (e < NE) {
    int s = src[e], t = dst[e];
    float wv = w[e];
    int p = atomicAdd(&cur_f[t], 1); col_f[p] = s; w_f[p] = wv;
    int q = atomicAdd(&cur_b[s], 1); col_b[q] = t; w_b[q] = wv;
  }
}

// ---------------- init linear ----------------
__global__ void k_init(const float* __restrict__ x, const float* __restrict__ iw,
                       const float* __restrict__ ib, float* __restrict__ h) {
  int idx = blockIdx.x * 256 + threadIdx.x;
  if (idx >= BN * 13 * 32) return;
  int c = idx & 31;
  int r = idx >> 5;          // r = tau*BN + n
  int n = r % BN;
  int tau = r / BN;
  float x0 = x[(n * 13 + tau) * 2 + 0];
  float x1 = x[(n * 13 + tau) * 2 + 1];
  h[idx] = fmaf(x0, iw[c], fmaf(x1, iw[32 + c], ib[c]));
}

// ---------------- weight pre-pack (bf16 B^T for all MFMA GEMMs) ----------------
__global__ void k_pack(const float* __restrict__ skip_w, const float* __restrict__ skip_b,
                       const float* __restrict__ w0, const float* __restrict__ w1,
                       const float* __restrict__ gcn_w,
                       unsigned short* __restrict__ SWb, unsigned short* __restrict__ W0T,
                       unsigned short* __restrict__ W1T, float* __restrict__ bsum,
                       unsigned short* __restrict__ GgT) {
  int id = blockIdx.x * 256 + threadIdx.x;
  if (id < 65536) {          // SWb[j][k=l*32+c] = skip_w[l][j][c]
    int j = id >> 8, k = id & 255;
    SWb[id] = to_bf16(skip_w[((k >> 5) * 256 + j) * 32 + (k & 31)]);
  }
  if (id < 131072) {         // W0T[jo][k] = w0[k][jo]
    int jo = id >> 8, k = id & 255;
    W0T[id] = to_bf16(w0[k * 512 + jo]);
  }
  if (id < 8192) {           // W1T[n][k] = w1[k][n], n padded to 16
    int n = id >> 9, k = id & 511;
    W1T[id] = (n < 12) ? to_bf16(w1[k * 12 + n]) : (unsigned short)0;
  }
  if (id < 256) {
    float s = 0.f;
    for (int l = 0; l < 8; ++l) s += skip_b[l * 256 + id];
    bsum[id] = s;
  }
  if (id < 49152) {          // GgT[l][co][k=a*32+ci] = gcn_w[l][a][ci][co]
    int l = id / 6144, rem = id % 6144;
    int co = rem / 192, k = rem % 192;
    int a = k >> 5, ci = k & 31;
    GgT[id] = to_bf16(gcn_w[((l * 6 + a) * 32 + ci) * 32 + co]);
  }
}

// ---------------- gated TCN: writes bf16 t, node-major padded ----------------
template<int LIN, int D, int TPAD>
__global__ __launch_bounds__(256) void k_tcn(const float* __restrict__ h_in, unsigned short* __restrict__ t_out,
    const float* __restrict__ fw, const float* __restrict__ fb,
    const float* __restrict__ gw, const float* __restrict__ gb) {
  constexpr int LOUT = LIN - D;
  __shared__ __align__(16) float wq[32 * 32 * 4];   // [(ci*32+co)*4 + {f0,f1,g0,g1}]
  __shared__ float hl[8][LIN * 32];
  int tid = threadIdx.x;
  for (int f = tid; f < 4096; f += 256) {
    int e = f & 3, co = (f >> 2) & 31, ci = f >> 7;
    const float* srcw = (e < 2) ? fw : gw;
    wq[f] = srcw[(co * 32 + ci) * 2 + (e & 1)];
  }
  int n0 = blockIdx.x * 8;
  for (int i = tid; i < 8 * LIN * 32; i += 256) {
    int c = i & 31, r = i >> 5;
    int nl = r / LIN, tau = r % LIN;
    hl[nl][tau * 32 + c] = h_in[(tau * BN + n0 + nl) * 32 + c];
  }
  __syncthreads();
  int nl = tid >> 5, co = tid & 31;
  int n = n0 + nl;
  float accf[LOUT], accg[LOUT];
  float fbv = fb[co], gbv = gb[co];
#pragma unroll
  for (int j = 0; j < LOUT; ++j) { accf[j] = fbv; accg[j] = gbv; }
#pragma unroll
  for (int ci = 0; ci < 32; ++ci) {
    float4 wv = *(const float4*)&wq[(ci * 32 + co) * 4];
    float xr[LIN];
#pragma unroll
    for (int t = 0; t < LIN; ++t) xr[t] = hl[nl][t * 32 + ci];
#pragma unroll
    for (int j = 0; j < LOUT; ++j) {
      accf[j] = fmaf(xr[j], wv.x, accf[j]);
      accf[j] = fmaf(xr[j + D], wv.y, accf[j]);
      accg[j] = fmaf(xr[j], wv.z, accg[j]);
      accg[j] = fmaf(xr[j + D], wv.w, accg[j]);
    }
  }
#pragma unroll
  for (int j = 0; j < LOUT; ++j) {
    float v = fast_tanh(accf[j]) * fast_sig(accg[j]);
    t_out[(n * TPAD + j) * 32 + co] = to_bf16(v);
  }
}

// ---------------- diffusion conv: gather (bf16) -> MFMA 32x32xK192 -> residual ----------------
__device__ __forceinline__ void bf4_fma(uint2 u, float w1, float4* A) {
  float v0 = __uint_as_float(u.x << 16);
  float v1 = __uint_as_float(u.x & 0xFFFF0000u);
  float v2 = __uint_as_float(u.y << 16);
  float v3 = __uint_as_float(u.y & 0xFFFF0000u);
  float w2 = w1 * w1, w3 = w2 * w1;
  A[0].x = fmaf(w1, v0, A[0].x); A[0].y = fmaf(w1, v1, A[0].y);
  A[0].z = fmaf(w1, v2, A[0].z); A[0].w = fmaf(w1, v3, A[0].w);
  A[1].x = fmaf(w2, v0, A[1].x); A[1].y = fmaf(w2, v1, A[1].y);
  A[1].z = fmaf(w2, v2, A[1].z); A[1].w = fmaf(w2, v3, A[1].w);
  A[2].x = fmaf(w3, v0, A[2].x); A[2].y = fmaf(w3, v1, A[2].y);
  A[2].z = fmaf(w3, v2, A[2].z); A[2].w = fmaf(w3, v3, A[2].w);
}

template<int TPAD>
__device__ __forceinline__ void gather_dir(const unsigned short* __restrict__ t_in,
    int e0, int e1, const int* __restrict__ col, const float* __restrict__ warr,
    int lane32, int rowoff, float4* A) {
  for (int base = e0; base < e1; base += 32) {
    int idx = base + lane32;
    int cv = 0; float wv = 0.f;
    if (idx < e1) { cv = col[idx]; wv = warr[idx]; }
    int cnt = min(32, e1 - base);
    int b = 0;
    for (; b + 8 <= cnt; b += 8) {
      uint2 u[8]; float w1[8];
#pragma unroll
      for (int k = 0; k < 8; ++k) {
        int s = __shfl(cv, b + k, 32);
        w1[k] = __shfl(wv, b + k, 32);
        u[k] = *(const uint2*)(t_in + s * (TPAD * 32) + rowoff);
      }
#pragma unroll
      for (int k = 0; k < 8; ++k) bf4_fma(u[k], w1[k], A);
    }
    for (; b < cnt; ++b) {
      int s = __shfl(cv, b, 32);
      float ww = __shfl(wv, b, 32);
      uint2 u = *(const uint2*)(t_in + s * (TPAD * 32) + rowoff);
      bf4_fma(u, ww, A);
    }
  }
}

#define ZSTRIDE 200   // halves; 400 B rows -> bank offset 4*m, m and m+8 alias = 2-way = free

template<int LOUT, int D, int TPAD>
__global__ __launch_bounds__(256) void k_agg(const unsigned short* __restrict__ t_in,
    const float* __restrict__ h_in, float* __restrict__ h_out, float* __restrict__ lastcol,
    const int* __restrict__ row_f, const int* __restrict__ col_f, const float* __restrict__ w_f,
    const int* __restrict__ row_b, const int* __restrict__ col_b, const float* __restrict__ w_b,
    const unsigned short* __restrict__ WgT,   // [32][192] bf16 B^T for this layer
    const float* __restrict__ bias) {
  __shared__ __align__(16) unsigned short Zl[32 * ZSTRIDE];   // 12.8 KB
  int tid = threadIdx.x;
  int nl = tid >> 5, lane32 = tid & 31;
  int tl = lane32 >> 3;              // local tau 0..3
  int c4 = (lane32 & 7) << 2;        // 4-channel group
  int n = blockIdx.x * 8 + nl;       // BN % 8 == 0
  int tau0 = blockIdx.y * 4;
  int rowoff = (tau0 + tl) * 32 + c4;
  int ef0 = row_f[n], ef1 = row_f[n + 1];
  int eb0 = row_b[n], eb1 = row_b[n + 1];
  float4 acc[6];
#pragma unroll
  for (int a = 0; a < 6; ++a) acc[a] = make_float4(0.f, 0.f, 0.f, 0.f);
  gather_dir<TPAD>(t_in, ef0, ef1, col_f, w_f, lane32, rowoff, acc + 0);
  gather_dir<TPAD>(t_in, eb0, eb1, col_b, w_b, lane32, rowoff, acc + 3);
  // z -> LDS as bf16 A-tile: Zl[m = nl*4+tl][k = a*32 + c4 .. +3]
  int m = nl * 4 + tl;
#pragma unroll
  for (int a = 0; a < 6; ++a) {
    ushort4 pk;
    pk.x = to_bf16(acc[a].x); pk.y = to_bf16(acc[a].y);
    pk.z = to_bf16(acc[a].z); pk.w = to_bf16(acc[a].w);
    *(ushort4*)(&Zl[m * ZSTRIDE + a * 32 + c4]) = pk;
  }
  __syncthreads();
  // MFMA: D[32 m][32 co] = Z[32][192] @ Wg[192][32]; wave -> (mt, nt) quadrant
  int wave = tid >> 6, lane = tid & 63;
  int m16 = lane & 15, q = lane >> 4;
  int mt = wave >> 1, nt = wave & 1;
  f32x4 dacc = (f32x4){0.f, 0.f, 0.f, 0.f};
#pragma unroll
  for (int ks = 0; ks < 6; ++ks) {
    bf16x8 av = *(const bf16x8*)(&Zl[(mt * 16 + m16) * ZSTRIDE + ks * 32 + q * 8]);
    bf16x8 bv = *(const bf16x8*)(WgT + (nt * 16 + m16) * 192 + ks * 32 + q * 8);
    dacc = mfma16(av, bv, dacc);
  }
  int co = nt * 16 + m16;
  float bco = bias[co];
#pragma unroll
  for (int r = 0; r < 4; ++r) {
    int mm = mt * 16 + q * 4 + r;             // C/D: col=lane&15, row=q*4+r (m89/m91)
    int node = blockIdx.x * 8 + (mm >> 2);
    int tau = tau0 + (mm & 3);
    if (tau < LOUT) {
      float rres = h_in[((tau + D) * BN + node) * 32 + co];   // residual
      float o = dacc[r] + bco + rres;
      h_out[(tau * BN + node) * 32 + co] = o;
      if (tau == LOUT - 1) lastcol[node * 32 + co] = o;
    }
  }
}

// ------------- fused MFMA head -------------
__device__ __forceinline__ bf16x8 ldsA(const unsigned short* buf, int stride, int row, int ks, int q) {
  int unit = ks * 4 + q;
  int addr = row * stride + ((unit ^ (row & 7)) << 3);
  return *(const bf16x8*)(buf + addr);
}

__global__ __launch_bounds__(256) void k_final(const float* __restrict__ lastcol,
    const unsigned short* __restrict__ SWb, const unsigned short* __restrict__ W0T,
    const unsigned short* __restrict__ W1T, const float* __restrict__ bsum,
    const float* __restrict__ b0, const float* __restrict__ b1,
    float* __restrict__ out) {
  __shared__ __align__(16) unsigned short Z[32 * 256];   // GEMM1 A, then relu(skip) (GEMM2 A)
  __shared__ __align__(16) unsigned short H[32 * 512];   // GEMM3 A
  int tid = threadIdx.x;
  int wave = tid >> 6, lane = tid & 63;
  int m16 = lane & 15, q = lane >> 4;
  int n0 = blockIdx.x * 32;
#pragma unroll
  for (int it = 0; it < 32; ++it) {
    int id = it * 256 + tid;
    int m = id >> 8, k = id & 255;
    float v = lastcol[((k >> 5) * BN + n0 + m) * 32 + (k & 31)];
    Z[m * 256 + (((k >> 3) ^ (m & 7)) << 3) + (k & 7)] = to_bf16(v);
  }
  __syncthreads();
  f32x4 acc1[2][4];
#pragma unroll
  for (int mt = 0; mt < 2; ++mt)
#pragma unroll
    for (int i = 0; i < 4; ++i) acc1[mt][i] = (f32x4){0.f, 0.f, 0.f, 0.f};
#pragma unroll
  for (int ks = 0; ks < 8; ++ks) {
    bf16x8 a0 = ldsA(Z, 256, m16, ks, q);
    bf16x8 a1 = ldsA(Z, 256, 16 + m16, ks, q);
#pragma unroll
    for (int i = 0; i < 4; ++i) {
      int j = (wave * 4 + i) * 16 + m16;
      bf16x8 b = *(const bf16x8*)(SWb + j * 256 + ks * 32 + q * 8);
      acc1[0][i] = mfma16(a0, b, acc1[0][i]);
      acc1[1][i] = mfma16(a1, b, acc1[1][i]);
    }
  }
  __syncthreads();
#pragma unroll
  for (int i = 0; i < 4; ++i) {
    int j = (wave * 4 + i) * 16 + m16;
    float bs = bsum[j];
#pragma unroll
    for (int mt = 0; mt < 2; ++mt)
#pragma unroll
      for (int r = 0; r < 4; ++r) {
        int row = mt * 16 + q * 4 + r;
        float v = fmaxf(acc1[mt][i][r] + bs, 0.f);
        Z[row * 256 + (((j >> 3) ^ (row & 7)) << 3) + (j & 7)] = to_bf16(v);
      }
  }
  __syncthreads();
  f32x4 acc2[2][8];
#pragma unroll
  for (int mt = 0; mt < 2; ++mt)
#pragma unroll
    for (int i = 0; i < 8; ++i) acc2[mt][i] = (f32x4){0.f, 0.f, 0.f, 0.f};
#pragma unroll
  for (int ks = 0; ks < 8; ++ks) {
    bf16x8 a0 = ldsA(Z, 256, m16, ks, q);
    bf16x8 a1 = ldsA(Z, 256, 16 + m16, ks, q);
#pragma unroll
    for (int i = 0; i < 8; ++i) {
      int jo = (wave * 8 + i) * 16 + m16;
      bf16x8 b = *(const bf16x8*)(W0T + jo * 256 + ks * 32 + q * 8);
      acc2[0][i] = mfma16(a0, b, acc2[0][i]);
      acc2[1][i] = mfma16(a1, b, acc2[1][i]);
    }
  }
#pragma unroll
  for (int i = 0; i < 8; ++i) {
    int jo = (wave * 8 + i) * 16 + m16;
    float b0v = b0[jo];
#pragma unroll
    for (int mt = 0; mt < 2; ++mt)
#pragma unroll
      for (int r = 0; r < 4; ++r) {
        int row = mt * 16 + q * 4 + r;
        float v = fmaxf(acc2[mt][i][r] + b0v, 0.f);
        H[row * 512 + (((jo >> 3) ^ (row & 7)) << 3) + (jo & 7)] = to_bf16(v);
      }
  }
  __syncthreads();
  if (wave < 2) {
    f32x4 acc3 = (f32x4){0.f, 0.f, 0.f, 0.f};
#pragma unroll
    for (int ks = 0; ks < 16; ++ks) {
      bf16x8 a = ldsA(H, 512, wave * 16 + m16, ks, q);
      bf16x8 b = *(const bf16x8*)(W1T + m16 * 512 + ks * 32 + q * 8);
      acc3 = mfma16(a, b, acc3);
    }
    if (m16 < 12) {
      float bv = b1[m16];
#pragma unroll
      for (int r = 0; r < 4; ++r)
        out[(n0 + wave * 16 + q * 4 + r) * 12 + m16] = acc3[r] + bv;
    }
  }
}

extern "C" void kernel_launch(void* const* d_in, const int* in_sizes, int n_in,
                              void* d_out, int out_size, void* d_ws, size_t ws_size,
                              hipStream_t stream) {
  const float* x      = (const float*)d_in[0];
  const int*   esrc   = (const int*)d_in[1];
  const int*   edst   = (const int*)d_in[2];
  const float* ew     = (const float*)d_in[3];
  const float* init_w = (const float*)d_in[4];
  const float* init_b = (const float*)d_in[5];
  const float* filt_w = (const float*)d_in[6];
  const float* filt_b = (const float*)d_in[7];
  const float* gate_w = (const float*)d_in[8];
  const float* gate_b = (const float*)d_in[9];
  const float* gcn_w  = (const float*)d_in[10];
  const float* gcn_b  = (const float*)d_in[11];
  const float* skip_w = (const float*)d_in[12];
  const float* skip_b = (const float*)d_in[13];
  const float* w0     = (const float*)d_in[14];
  const float* b0     = (const float*)d_in[15];
  const float* w1     = (const float*)d_in[16];
  const float* b1     = (const float*)d_in[17];
  float* out = (float*)d_out;

  float* base = (float*)d_ws;
  float* hA      = base;                       // 13*BN*32 f32
  float* hB      = hA + 13 * BN * 32;          // 13*BN*32 f32
  float* tbuf    = hB + 13 * BN * 32;          // 12*BN*32 f32 region (bf16 t + packed weights)
  float* lastcol = tbuf + 12 * BN * 32;        // 8*BN*32 f32
  int* row_f = (int*)(lastcol + 8 * BN * 32);  // BN+1
  int* row_b = row_f + (BN + 1);               // BN+1
  int* cur_f = row_b + (BN + 1);               // BN
  int* cur_b = cur_f + BN;                     // BN
  int* col_f = cur_b + BN;                     // NE
  int* col_b = col_f + NE;                     // NE
  float* wgt_f = (float*)(col_b + NE);         // NE
  float* wgt_b = wgt_f + NE;                   // NE
  unsigned short* tbuf_u = (unsigned short*)tbuf;
  // packed bf16 weights live in tbuf's unused upper half (t uses <= 12*BN*32 halves of 24*BN*32)
  unsigned short* SWb = tbuf_u + 16 * BN * 32;   // 65536 halves
  unsigned short* W0T = SWb + 65536;             // 131072 halves
  unsigned short* W1T = W0T + 131072;            // 8192 halves
  float* bsumv = (float*)(W1T + 8192);           // 256 f32
  unsigned short* GgT = (unsigned short*)(bsumv + 256);  // 49152 halves

  hipMemsetAsync(cur_f, 0, 2 * BN * sizeof(int), stream);
  const int egrid = (NE + 255) / 256;
  k_count<<<egrid, 256, 0, stream>>>(esrc, edst, cur_f, cur_b);
  k_scan<<<1, 1024, 0, stream>>>(cur_f, row_f, cur_b, row_b);
  k_fill<<<egrid, 256, 0, stream>>>(esrc, edst, ew, cur_f, col_f, wgt_f, cur_b, col_b, wgt_b);
  k_init<<<(BN * 13 * 32 + 255) / 256, 256, 0, stream>>>(x, init_w, init_b, hA);
  k_pack<<<512, 256, 0, stream>>>(skip_w, skip_b, w0, w1, gcn_w, SWb, W0T, W1T, bsumv, GgT);

  const int ngrid = BN / 8;
#define LAYER(l, LIN, DD, TP, hin, hout) \
  k_tcn<LIN, DD, TP><<<ngrid, 256, 0, stream>>>(hin, tbuf_u, filt_w + l * 2048, filt_b + l * 32, \
                                                gate_w + l * 2048, gate_b + l * 32); \
  k_agg<LIN - DD, DD, TP><<<dim3(ngrid, ((LIN - DD) + 3) / 4), 256, 0, stream>>>(tbuf_u, hin, hout, \
      lastcol + l * BN * 32, row_f, col_f, wgt_f, row_b, col_b, wgt_b, GgT + l * 6144, gcn_b + l * 32);

  LAYER(0, 13, 1, 12, hA, hB)
  LAYER(1, 12, 2, 12, hB, hA)
  LAYER(2, 10, 1, 12, hA, hB)
  LAYER(3,  9, 2, 12, hB, hA)
  LAYER(4,  7, 1,  8, hA, hB)
  LAYER(5,  6, 2,  8, hB, hA)
  LAYER(6,  4, 1,  4, hA, hB)
  LAYER(7,  3, 2,  4, hB, hA)
#undef LAYER

  k_final<<<BN / 32, 256, 0, stream>>>(lastcol, SWb, W0T, W1T, bsumv, b0, b1, out);
}

// Round 5
// 758.715 us; speedup vs baseline: 2.7706x; 1.0045x over previous
//
#include <hip/hip_runtime.h>

#define BN 13248
#define NE 211968

typedef __attribute__((ext_vector_type(8))) short bf16x8;
typedef __attribute__((ext_vector_type(4))) float f32x4;

__device__ __forceinline__ f32x4 mfma16(bf16x8 a, bf16x8 b, f32x4 c) {
  return __builtin_amdgcn_mfma_f32_16x16x32_bf16(a, b, c, 0, 0, 0);
}

__device__ __forceinline__ unsigned short to_bf16(float v) {
  unsigned bits = __float_as_uint(v);
  return (unsigned short)((bits + 0x7FFFu + ((bits >> 16) & 1u)) >> 16);   // RNE
}

__device__ __forceinline__ float fast_tanh(float x) {
  float e2 = __expf(2.f * x);
  return 1.f - 2.f / (e2 + 1.f);   // inf-safe
}
__device__ __forceinline__ float fast_sig(float x) {
  return 1.f / (1.f + __expf(-x));
}

// ---------------- CSR build ----------------
__global__ void k_count(const int* __restrict__ src, const int* __restrict__ dst,
                        int* __restrict__ cur_f, int* __restrict__ cur_b) {
  int e = blockIdx.x * 256 + threadIdx.x;
  if (e < NE) {
    atomicAdd(&cur_f[dst[e]], 1);
    atomicAdd(&cur_b[src[e]], 1);
  }
}

__global__ void k_scan(int* __restrict__ cur_f, int* __restrict__ row_f,
                       int* __restrict__ cur_b, int* __restrict__ row_b) {
  __shared__ int sdata[1024];
  int tid = threadIdx.x;
  for (int which = 0; which < 2; ++which) {
    int* cnt = which ? cur_b : cur_f;
    int* row = which ? row_b : row_f;
    int base = tid * 13;
    int vals[13];
    int tot = 0;
    for (int k = 0; k < 13; ++k) {
      int idx = base + k;
      int v = (idx < BN) ? cnt[idx] : 0;
      vals[k] = v; tot += v;
    }
    sdata[tid] = tot;
    __syncthreads();
    for (int off = 1; off < 1024; off <<= 1) {
      int add = (tid >= off) ? sdata[tid - off] : 0;
      __syncthreads();
      sdata[tid] += add;
      __syncthreads();
    }
    int running = sdata[tid] - tot;  // exclusive
    for (int k = 0; k < 13; ++k) {
      int idx = base + k;
      if (idx < BN) { row[idx] = running; cnt[idx] = running; running += vals[k]; }
    }
    if (tid == 1023) row[BN] = sdata[1023];
    __syncthreads();
  }
}

__global__ void k_fill(const int* __restrict__ src, const int* __restrict__ dst,
                       const float* __restrict__ w,
                       int* __restrict__ cur_f, int* __restrict__ col_f, float* __restrict__ w_f,
                       int* __restrict__ cur_b, int* __restrict__ col_b, float* __restrict__ w_b) {
  int e = blockIdx.x * 256 + threadIdx.x;
  if (e < NE) {
    int s = src[e], t = dst[e];
    float wv = w[e];
    int p = atomicAdd(&cur_f[t], 1); col_f[p] = s; w_f[p] = wv;
    int q = atomicAdd(&cur_b[s], 1); col_b[q] = t; w_b[q] = wv;
  }
}

// ---------------- init linear ----------------
__global__ void k_init(const float* __restrict__ x, const float* __restrict__ iw,
                       const float* __restrict__ ib, float* __restrict__ h) {
  int idx = blockIdx.x * 256 + threadIdx.x;
  if (idx >= BN * 13 * 32) return;
  int c = idx & 31;
  int r = idx >> 5;          // r = tau*BN + n
  int n = r % BN;
  int tau = r / BN;
  float x0 = x[(n * 13 + tau) * 2 + 0];
  float x1 = x[(n * 13 + tau) * 2 + 1];
  h[idx] = fmaf(x0, iw[c], fmaf(x1, iw[32 + c], ib[c]));
}

// ---------------- weight pre-pack (bf16 B^T for all MFMA GEMMs) ----------------
__global__ void k_pack(const float* __restrict__ skip_w, const float* __restrict__ skip_b,
                       const float* __restrict__ w0, const float* __restrict__ w1,
                       const float* __restrict__ gcn_w,
                       unsigned short* __restrict__ SWb, unsigned short* __restrict__ W0T,
                       unsigned short* __restrict__ W1T, float* __restrict__ bsum,
                       unsigned short* __restrict__ GgT) {
  int id = blockIdx.x * 256 + threadIdx.x;
  if (id < 65536) {          // SWb[j][k=l*32+c] = skip_w[l][j][c]
    int j = id >> 8, k = id & 255;
    SWb[id] = to_bf16(skip_w[((k >> 5) * 256 + j) * 32 + (k & 31)]);
  }
  if (id < 131072) {         // W0T[jo][k] = w0[k][jo]
    int jo = id >> 8, k = id & 255;
    W0T[id] = to_bf16(w0[k * 512 + jo]);
  }
  if (id < 8192) {           // W1T[n][k] = w1[k][n], n padded to 16
    int n = id >> 9, k = id & 511;
    W1T[id] = (n < 12) ? to_bf16(w1[k * 12 + n]) : (unsigned short)0;
  }
  if (id < 256) {
    float s = 0.f;
    for (int l = 0; l < 8; ++l) s += skip_b[l * 256 + id];
    bsum[id] = s;
  }
  if (id < 49152) {          // GgT[l][co][k=a*32+ci] = gcn_w[l][a][ci][co]
    int l = id / 6144, rem = id % 6144;
    int co = rem / 192, k = rem % 192;
    int a = k >> 5, ci = k & 31;
    GgT[id] = to_bf16(gcn_w[((l * 6 + a) * 32 + ci) * 32 + co]);
  }
}

// ---------------- gated TCN: writes bf16 t, node-major, zero-padded to TPAD ----------------
template<int LIN, int D, int TPAD>
__global__ __launch_bounds__(256) void k_tcn(const float* __restrict__ h_in, unsigned short* __restrict__ t_out,
    const float* __restrict__ fw, const float* __restrict__ fb,
    const float* __restrict__ gw, const float* __restrict__ gb) {
  constexpr int LOUT = LIN - D;
  __shared__ __align__(16) float wq[32 * 32 * 4];   // [(ci*32+co)*4 + {f0,f1,g0,g1}]
  __shared__ float hl[8][LIN * 32];
  int tid = threadIdx.x;
  for (int f = tid; f < 4096; f += 256) {
    int e = f & 3, co = (f >> 2) & 31, ci = f >> 7;
    const float* srcw = (e < 2) ? fw : gw;
    wq[f] = srcw[(co * 32 + ci) * 2 + (e & 1)];
  }
  int n0 = blockIdx.x * 8;
  for (int i = tid; i < 8 * LIN * 32; i += 256) {
    int c = i & 31, r = i >> 5;
    int nl = r / LIN, tau = r % LIN;
    hl[nl][tau * 32 + c] = h_in[(tau * BN + n0 + nl) * 32 + c];
  }
  __syncthreads();
  int nl = tid >> 5, co = tid & 31;
  int n = n0 + nl;
  float accf[LOUT], accg[LOUT];
  float fbv = fb[co], gbv = gb[co];
#pragma unroll
  for (int j = 0; j < LOUT; ++j) { accf[j] = fbv; accg[j] = gbv; }
#pragma unroll
  for (int ci = 0; ci < 32; ++ci) {
    float4 wv = *(const float4*)&wq[(ci * 32 + co) * 4];
    float xr[LIN];
#pragma unroll
    for (int t = 0; t < LIN; ++t) xr[t] = hl[nl][t * 32 + ci];
#pragma unroll
    for (int j = 0; j < LOUT; ++j) {
      accf[j] = fmaf(xr[j], wv.x, accf[j]);
      accf[j] = fmaf(xr[j + D], wv.y, accf[j]);
      accg[j] = fmaf(xr[j], wv.z, accg[j]);
      accg[j] = fmaf(xr[j + D], wv.w, accg[j]);
    }
  }
#pragma unroll
  for (int j = 0; j < TPAD; ++j) {
    float v = (j < LOUT) ? fast_tanh(accf[j < LOUT ? j : 0]) * fast_sig(accg[j < LOUT ? j : 0]) : 0.f;
    t_out[(n * TPAD + j) * 32 + co] = (j < LOUT) ? to_bf16(v) : (unsigned short)0;
  }
}

// ---------------- diffusion conv: one dispatch per layer, all tau ----------------
__device__ __forceinline__ void bf4_fma3(uint2 u, float w1, float w2, float w3,
                                         float4* A0, float4* A1, float4* A2) {
  float v0 = __uint_as_float(u.x << 16);
  float v1 = __uint_as_float(u.x & 0xFFFF0000u);
  float v2 = __uint_as_float(u.y << 16);
  float v3 = __uint_as_float(u.y & 0xFFFF0000u);
  A0->x = fmaf(w1, v0, A0->x); A0->y = fmaf(w1, v1, A0->y);
  A0->z = fmaf(w1, v2, A0->z); A0->w = fmaf(w1, v3, A0->w);
  A1->x = fmaf(w2, v0, A1->x); A1->y = fmaf(w2, v1, A1->y);
  A1->z = fmaf(w2, v2, A1->z); A1->w = fmaf(w2, v3, A1->w);
  A2->x = fmaf(w3, v0, A2->x); A2->y = fmaf(w3, v1, A2->y);
  A2->z = fmaf(w3, v2, A2->z); A2->w = fmaf(w3, v3, A2->w);
}

// A: [3][NT] accumulators for one direction (hops 1..3)
template<int TPAD, int NT>
__device__ __forceinline__ void gather_dir(const unsigned short* __restrict__ t_in,
    int e0, int e1, const int* __restrict__ col, const float* __restrict__ warr,
    int lane32, int rowoff0, float4 (*A)[NT]) {
  for (int base = e0; base < e1; base += 32) {
    int idx = base + lane32;
    int cv = 0; float wv = 0.f;
    if (idx < e1) { cv = col[idx]; wv = warr[idx]; }
    int cnt = min(32, e1 - base);
    int b = 0;
    for (; b + 4 <= cnt; b += 4) {
      uint2 u[4][NT]; float w1[4];
#pragma unroll
      for (int k = 0; k < 4; ++k) {
        int s = __shfl(cv, b + k, 32);
        w1[k] = __shfl(wv, b + k, 32);
        const unsigned short* p = t_in + s * (TPAD * 32) + rowoff0;
#pragma unroll
        for (int j = 0; j < NT; ++j) u[k][j] = *(const uint2*)(p + j * 32);
      }
#pragma unroll
      for (int k = 0; k < 4; ++k) {
        float w2 = w1[k] * w1[k], w3 = w2 * w1[k];
#pragma unroll
        for (int j = 0; j < NT; ++j)
          bf4_fma3(u[k][j], w1[k], w2, w3, &A[0][j], &A[1][j], &A[2][j]);
      }
    }
    for (; b < cnt; ++b) {
      int s = __shfl(cv, b, 32);
      float ww = __shfl(wv, b, 32);
      float w2 = ww * ww, w3 = w2 * ww;
      const unsigned short* p = t_in + s * (TPAD * 32) + rowoff0;
#pragma unroll
      for (int j = 0; j < NT; ++j) {
        uint2 u = *(const uint2*)(p + j * 32);
        bf4_fma3(u, ww, w2, w3, &A[0][j], &A[1][j], &A[2][j]);
      }
    }
  }
}

#define ZSTRIDE 200   // halves; rows offset banks by 4 -> worst 2-way (free)

template<int LOUT, int D, int TPAD>
__global__ __launch_bounds__(256, 3) void k_agg(const unsigned short* __restrict__ t_in,
    const float* __restrict__ h_in, float* __restrict__ h_out, float* __restrict__ lastcol,
    const int* __restrict__ row_f, const int* __restrict__ col_f, const float* __restrict__ w_f,
    const int* __restrict__ row_b, const int* __restrict__ col_b, const float* __restrict__ w_b,
    const unsigned short* __restrict__ WgT,   // [32][192] bf16 B^T for this layer
    const float* __restrict__ bias) {
  constexpr int NT = TPAD / 4;
  __shared__ __align__(16) unsigned short Zl[8 * TPAD * ZSTRIDE];   // up to 38.4 KB
  int tid = threadIdx.x;
  int nl = tid >> 5, lane32 = tid & 31;
  int tl = lane32 >> 3;              // tau slot 0..3; lane covers tau = tl*NT + j
  int c4 = (lane32 & 7) << 2;        // 4-channel group
  int n0 = blockIdx.x * 8;
  int n = n0 + nl;                   // BN % 8 == 0
  int rowoff0 = (tl * NT) * 32 + c4;
  int ef0 = row_f[n], ef1 = row_f[n + 1];
  int eb0 = row_b[n], eb1 = row_b[n + 1];
  float4 accf[3][NT], accb[3][NT];
#pragma unroll
  for (int a = 0; a < 3; ++a)
#pragma unroll
    for (int j = 0; j < NT; ++j) {
      accf[a][j] = make_float4(0.f, 0.f, 0.f, 0.f);
      accb[a][j] = make_float4(0.f, 0.f, 0.f, 0.f);
    }
  gather_dir<TPAD, NT>(t_in, ef0, ef1, col_f, w_f, lane32, rowoff0, accf);
  gather_dir<TPAD, NT>(t_in, eb0, eb1, col_b, w_b, lane32, rowoff0, accb);
  // z -> LDS bf16 A-tile: row m = nl*TPAD + tl*NT + j, k = a*32 + c4
#pragma unroll
  for (int j = 0; j < NT; ++j) {
    int m = nl * TPAD + tl * NT + j;
#pragma unroll
    for (int a = 0; a < 3; ++a) {
      ushort4 pf, pb;
      pf.x = to_bf16(accf[a][j].x); pf.y = to_bf16(accf[a][j].y);
      pf.z = to_bf16(accf[a][j].z); pf.w = to_bf16(accf[a][j].w);
      pb.x = to_bf16(accb[a][j].x); pb.y = to_bf16(accb[a][j].y);
      pb.z = to_bf16(accb[a][j].z); pb.w = to_bf16(accb[a][j].w);
      *(ushort4*)(&Zl[m * ZSTRIDE + a * 32 + c4]) = pf;
      *(ushort4*)(&Zl[m * ZSTRIDE + (a + 3) * 32 + c4]) = pb;
    }
  }
  __syncthreads();
  // MFMA: D[8*TPAD rows][32 co] = Z[8*TPAD][192] @ Wg[192][32]
  // TPAD units of (mt, nt); wave w takes units w*NT..w*NT+NT-1
  int wave = tid >> 6, lane = tid & 63;
  int m16 = lane & 15, q = lane >> 4;
#pragma unroll
  for (int i = 0; i < NT; ++i) {
    int u = wave * NT + i;
    int mt = u >> 1, nt = u & 1;
    f32x4 dacc = (f32x4){0.f, 0.f, 0.f, 0.f};
#pragma unroll
    for (int ks = 0; ks < 6; ++ks) {
      bf16x8 av = *(const bf16x8*)(&Zl[(mt * 16 + m16) * ZSTRIDE + ks * 32 + q * 8]);
      bf16x8 bv = *(const bf16x8*)(WgT + (nt * 16 + m16) * 192 + ks * 32 + q * 8);
      dacc = mfma16(av, bv, dacc);
    }
    int co = nt * 16 + m16;
    float bco = bias[co];
#pragma unroll
    for (int r = 0; r < 4; ++r) {
      int mm = mt * 16 + q * 4 + r;           // C/D: col=lane&15, row=q*4+r
      int node = n0 + mm / TPAD;
      int tau = mm % TPAD;
      if (tau < LOUT) {
        float rres = h_in[((tau + D) * BN + node) * 32 + co];   // residual
        float o = dacc[r] + bco + rres;
        h_out[(tau * BN + node) * 32 + co] = o;
        if (tau == LOUT - 1) lastcol[node * 32 + co] = o;
      }
    }
  }
}

// ------------- fused MFMA head -------------
__device__ __forceinline__ bf16x8 ldsA(const unsigned short* buf, int stride, int row, int ks, int q) {
  int unit = ks * 4 + q;
  int addr = row * stride + ((unit ^ (row & 7)) << 3);
  return *(const bf16x8*)(buf + addr);
}

__global__ __launch_bounds__(256) void k_final(const float* __restrict__ lastcol,
    const unsigned short* __restrict__ SWb, const unsigned short* __restrict__ W0T,
    const unsigned short* __restrict__ W1T, const float* __restrict__ bsum,
    const float* __restrict__ b0, const float* __restrict__ b1,
    float* __restrict__ out) {
  __shared__ __align__(16) unsigned short Z[32 * 256];   // GEMM1 A, then relu(skip) (GEMM2 A)
  __shared__ __align__(16) unsigned short H[32 * 512];   // GEMM3 A
  int tid = threadIdx.x;
  int wave = tid >> 6, lane = tid & 63;
  int m16 = lane & 15, q = lane >> 4;
  int n0 = blockIdx.x * 32;
#pragma unroll
  for (int it = 0; it < 32; ++it) {
    int id = it * 256 + tid;
    int m = id >> 8, k = id & 255;
    float v = lastcol[((k >> 5) * BN + n0 + m) * 32 + (k & 31)];
    Z[m * 256 + (((k >> 3) ^ (m & 7)) << 3) + (k & 7)] = to_bf16(v);
  }
  __syncthreads();
  f32x4 acc1[2][4];
#pragma unroll
  for (int mt = 0; mt < 2; ++mt)
#pragma unroll
    for (int i = 0; i < 4; ++i) acc1[mt][i] = (f32x4){0.f, 0.f, 0.f, 0.f};
#pragma unroll
  for (int ks = 0; ks < 8; ++ks) {
    bf16x8 a0 = ldsA(Z, 256, m16, ks, q);
    bf16x8 a1 = ldsA(Z, 256, 16 + m16, ks, q);
#pragma unroll
    for (int i = 0; i < 4; ++i) {
      int j = (wave * 4 + i) * 16 + m16;
      bf16x8 b = *(const bf16x8*)(SWb + j * 256 + ks * 32 + q * 8);
      acc1[0][i] = mfma16(a0, b, acc1[0][i]);
      acc1[1][i] = mfma16(a1, b, acc1[1][i]);
    }
  }
  __syncthreads();
#pragma unroll
  for (int i = 0; i < 4; ++i) {
    int j = (wave * 4 + i) * 16 + m16;
    float bs = bsum[j];
#pragma unroll
    for (int mt = 0; mt < 2; ++mt)
#pragma unroll
      for (int r = 0; r < 4; ++r) {
        int row = mt * 16 + q * 4 + r;
        float v = fmaxf(acc1[mt][i][r] + bs, 0.f);
        Z[row * 256 + (((j >> 3) ^ (row & 7)) << 3) + (j & 7)] = to_bf16(v);
      }
  }
  __syncthreads();
  f32x4 acc2[2][8];
#pragma unroll
  for (int mt = 0; mt < 2; ++mt)
#pragma unroll
    for (int i = 0; i < 8; ++i) acc2[mt][i] = (f32x4){0.f, 0.f, 0.f, 0.f};
#pragma unroll
  for (int ks = 0; ks < 8; ++ks) {
    bf16x8 a0 = ldsA(Z, 256, m16, ks, q);
    bf16x8 a1 = ldsA(Z, 256, 16 + m16, ks, q);
#pragma unroll
    for (int i = 0; i < 8; ++i) {
      int jo = (wave * 8 + i) * 16 + m16;
      bf16x8 b = *(const bf16x8*)(W0T + jo * 256 + ks * 32 + q * 8);
      acc2[0][i] = mfma16(a0, b, acc2[0][i]);
      acc2[1][i] = mfma16(a1, b, acc2[1][i]);
    }
  }
#pragma unroll
  for (int i = 0; i < 8; ++i) {
    int jo = (wave * 8 + i) * 16 + m16;
    float b0v = b0[jo];
#pragma unroll
    for (int mt = 0; mt < 2; ++mt)
#pragma unroll
      for (int r = 0; r < 4; ++r) {
        int row = mt * 16 + q * 4 + r;
        float v = fmaxf(acc2[mt][i][r] + b0v, 0.f);
        H[row * 512 + (((jo >> 3) ^ (row & 7)) << 3) + (jo & 7)] = to_bf16(v);
      }
  }
  __syncthreads();
  if (wave < 2) {
    f32x4 acc3 = (f32x4){0.f, 0.f, 0.f, 0.f};
#pragma unroll
    for (int ks = 0; ks < 16; ++ks) {
      bf16x8 a = ldsA(H, 512, wave * 16 + m16, ks, q);
      bf16x8 b = *(const bf16x8*)(W1T + m16 * 512 + ks * 32 + q * 8);
      acc3 = mfma16(a, b, acc3);
    }
    if (m16 < 12) {
      float bv = b1[m16];
#pragma unroll
      for (int r = 0; r < 4; ++r)
        out[(n0 + wave * 16 + q * 4 + r) * 12 + m16] = acc3[r] + bv;
    }
  }
}

extern "C" void kernel_launch(void* const* d_in, const int* in_sizes, int n_in,
                              void* d_out, int out_size, void* d_ws, size_t ws_size,
                              hipStream_t stream) {
  const float* x      = (const float*)d_in[0];
  const int*   esrc   = (const int*)d_in[1];
  const int*   edst   = (const int*)d_in[2];
  const float* ew     = (const float*)d_in[3];
  const float* init_w = (const float*)d_in[4];
  const float* init_b = (const float*)d_in[5];
  const float* filt_w = (const float*)d_in[6];
  const float* filt_b = (const float*)d_in[7];
  const float* gate_w = (const float*)d_in[8];
  const float* gate_b = (const float*)d_in[9];
  const float* gcn_w  = (const float*)d_in[10];
  const float* gcn_b  = (const float*)d_in[11];
  const float* skip_w = (const float*)d_in[12];
  const float* skip_b = (const float*)d_in[13];
  const float* w0     = (const float*)d_in[14];
  const float* b0     = (const float*)d_in[15];
  const float* w1     = (const float*)d_in[16];
  const float* b1     = (const float*)d_in[17];
  float* out = (float*)d_out;

  float* base = (float*)d_ws;
  float* hA      = base;                       // 13*BN*32 f32
  float* hB      = hA + 13 * BN * 32;          // 13*BN*32 f32
  float* tbuf    = hB + 13 * BN * 32;          // region reused: bf16 t (<=12*BN*32 halves) + packed weights
  float* lastcol = tbuf + 12 * BN * 32;        // 8*BN*32 f32
  int* row_f = (int*)(lastcol + 8 * BN * 32);  // BN+1
  int* row_b = row_f + (BN + 1);               // BN+1
  int* cur_f = row_b + (BN + 1);               // BN
  int* cur_b = cur_f + BN;                     // BN
  int* col_f = cur_b + BN;                     // NE
  int* col_b = col_f + NE;                     // NE
  float* wgt_f = (float*)(col_b + NE);         // NE
  float* wgt_b = wgt_f + NE;                   // NE
  unsigned short* tbuf_u = (unsigned short*)tbuf;
  unsigned short* SWb = tbuf_u + 16 * BN * 32;   // 65536 halves
  unsigned short* W0T = SWb + 65536;             // 131072 halves
  unsigned short* W1T = W0T + 131072;            // 8192 halves
  float* bsumv = (float*)(W1T + 8192);           // 256 f32
  unsigned short* GgT = (unsigned short*)(bsumv + 256);  // 49152 halves

  hipMemsetAsync(cur_f, 0, 2 * BN * sizeof(int), stream);
  const int egrid = (NE + 255) / 256;
  k_count<<<egrid, 256, 0, stream>>>(esrc, edst, cur_f, cur_b);
  k_scan<<<1, 1024, 0, stream>>>(cur_f, row_f, cur_b, row_b);
  k_fill<<<egrid, 256, 0, stream>>>(esrc, edst, ew, cur_f, col_f, wgt_f, cur_b, col_b, wgt_b);
  k_init<<<(BN * 13 * 32 + 255) / 256, 256, 0, stream>>>(x, init_w, init_b, hA);
  k_pack<<<512, 256, 0, stream>>>(skip_w, skip_b, w0, w1, gcn_w, SWb, W0T, W1T, bsumv, GgT);

  const int ngrid = BN / 8;
#define LAYER(l, LIN, DD, TP, hin, hout) \
  k_tcn<LIN, DD, TP><<<ngrid, 256, 0, stream>>>(hin, tbuf_u, filt_w + l * 2048, filt_b + l * 32, \
                                                gate_w + l * 2048, gate_b + l * 32); \
  k_agg<LIN - DD, DD, TP><<<ngrid, 256, 0, stream>>>(tbuf_u, hin, hout, \
      lastcol + l * BN * 32, row_f, col_f, wgt_f, row_b, col_b, wgt_b, GgT + l * 6144, gcn_b + l * 32);

  LAYER(0, 13, 1, 12, hA, hB)
  LAYER(1, 12, 2, 12, hB, hA)
  LAYER(2, 10, 1, 12, hA, hB)
  LAYER(3,  9, 2,  8, hB, hA)
  LAYER(4,  7, 1,  8, hA, hB)
  LAYER(5,  6, 2,  4, hB, hA)
  LAYER(6,  4, 1,  4, hA, hB)
  LAYER(7,  3, 2,  4, hB, hA)
#undef LAYER

  k_final<<<BN / 32, 256, 0, stream>>>(lastcol, SWb, W0T, W1T, bsumv, b0, b1, out);
}